// Round 11
// baseline (253.133 us; speedup 1.0000x reference)
//
#include <hip/hip_runtime.h>
#include <hip/hip_bf16.h>
#include <math.h>

using bf16 = __hip_bfloat16;
typedef short s16x8 __attribute__((ext_vector_type(8)));
typedef float f32x4 __attribute__((ext_vector_type(4)));
typedef float f32x16 __attribute__((ext_vector_type(16)));

#define LOG2E 1.4426950408889634f
// Q pre-scale: D^-0.5 * log2(e) so QK^T scores land directly in log2 domain.
#define QSCALE 0.18033688f

__device__ inline unsigned short f2bf(float f) {
    bf16 h = __float2bfloat16(f);
    return __builtin_bit_cast(unsigned short, h);
}

// async global->LDS, 16B per lane. Dest must be wave-linear (base + lane*16).
__device__ inline void gload_lds16(const void* g, void* l) {
    __builtin_amdgcn_global_load_lds(
        (const __attribute__((address_space(1))) void*)g,
        (__attribute__((address_space(3))) void*)l, 16, 0, 0);
}

__device__ inline unsigned cvtpk(float lo, float hi) {
    unsigned r;
    asm("v_cvt_pk_bf16_f32 %0, %1, %2" : "=v"(r) : "v"(lo), "v"(hi));
    return r;
}

// Build PV B-operand fragment from 8 in-lane P values (verified mapping).
__device__ inline s16x8 build_pfrag(float p0, float p1, float p2, float p3,
                                    float p4, float p5, float p6, float p7) {
    unsigned w01 = cvtpk(p0, p1);
    unsigned w23 = cvtpk(p2, p3);
    unsigned w45 = cvtpk(p4, p5);
    unsigned w67 = cvtpk(p6, p7);
    asm volatile("v_permlane32_swap_b32 %0, %1" : "+v"(w01), "+v"(w45));
    asm volatile("v_permlane32_swap_b32 %0, %1" : "+v"(w23), "+v"(w67));
    int4 t = {(int)w01, (int)w23, (int)w45, (int)w67};
    return __builtin_bit_cast(s16x8, t);
}

// ---------------------------------------------------------------------------
// Merged weight prep: all four W -> W^T bf16 in ONE launch.
// ---------------------------------------------------------------------------
__global__ __launch_bounds__(256) void transpose_all(
    const float* __restrict__ qkv_w, const float* __restrict__ proj_w,
    const float* __restrict__ fc1_w, const float* __restrict__ fc2_w,
    bf16* __restrict__ Wqkv, bf16* __restrict__ Wproj,
    bf16* __restrict__ Wfc1, bf16* __restrict__ Wfc2)
{
    int t = blockIdx.x;
    const float* in;
    bf16* out;
    int K, N, xt;
    if (t < 1728)      { in = qkv_w;  out = Wqkv;  K = 768;  N = 2304; xt = 72; }
    else if (t < 2304) { in = proj_w; out = Wproj; K = 768;  N = 768;  xt = 24; t -= 1728; }
    else if (t < 4608) { in = fc1_w;  out = Wfc1;  K = 768;  N = 3072; xt = 96; t -= 2304; }
    else               { in = fc2_w;  out = Wfc2;  K = 3072; N = 768;  xt = 24; t -= 4608; }
    const int bx = (t % xt) * 32;  // n
    const int by = (t / xt) * 32;  // k

    __shared__ float tile[32][33];
    const int tx = threadIdx.x, ty = threadIdx.y;  // 32 x 8
    #pragma unroll
    for (int i = 0; i < 32; i += 8)
        tile[ty + i][tx] = in[(size_t)(by + ty + i) * N + bx + tx];
    __syncthreads();
    #pragma unroll
    for (int i = 0; i < 32; i += 8)
        out[(size_t)(bx + ty + i) * K + by + tx] = __float2bfloat16(tile[tx][ty + i]);
}

// ---------------------------------------------------------------------------
// LayerNorm over C=768, fp32 in -> bf16 out. One 256-thread block per row.
// ---------------------------------------------------------------------------
__global__ __launch_bounds__(256) void ln_kernel(
    const float* __restrict__ x, const float* __restrict__ g,
    const float* __restrict__ bb, bf16* __restrict__ out)
{
    const int row = blockIdx.x;
    const float* xr = x + (size_t)row * 768;
    float v[3];
    float s = 0.f, s2 = 0.f;
    #pragma unroll
    for (int i = 0; i < 3; ++i) {
        v[i] = xr[threadIdx.x + i * 256];
        s += v[i];
        s2 += v[i] * v[i];
    }
    #pragma unroll
    for (int off = 1; off < 64; off <<= 1) {
        s += __shfl_xor(s, off);
        s2 += __shfl_xor(s2, off);
    }
    __shared__ float rs[4], rs2[4];
    const int wave = threadIdx.x >> 6;
    if ((threadIdx.x & 63) == 0) { rs[wave] = s; rs2[wave] = s2; }
    __syncthreads();
    s = rs[0] + rs[1] + rs[2] + rs[3];
    s2 = rs2[0] + rs2[1] + rs2[2] + rs2[3];
    const float mu = s * (1.f / 768.f);
    const float var = s2 * (1.f / 768.f) - mu * mu;
    const float r = rsqrtf(var + 1e-6f);
    bf16* orow = out + (size_t)row * 768;
    #pragma unroll
    for (int i = 0; i < 3; ++i) {
        const int col = threadIdx.x + i * 256;
        orow[col] = __float2bfloat16((v[i] - mu) * r * g[col] + bb[col]);
    }
}

// ---------------------------------------------------------------------------
// GEMM 128x128 (known-good): out = A @ Bt^T + bias (+ gelu / QKV scatter).
// EPI: 2 = bias+gelu -> bf16 ; 3 = fused QKV scatter.
// ---------------------------------------------------------------------------
template <int EPI>
__global__ __launch_bounds__(256) void gemm_bt(
    const bf16* __restrict__ A, const bf16* __restrict__ Bt,
    const float* __restrict__ bias,
    void* __restrict__ outp, const int* __restrict__ mask,
    bf16* __restrict__ Qb, bf16* __restrict__ Kb, bf16* __restrict__ Vt,
    int M, int N, int K)
{
    __shared__ alignas(16) char smem[32768];
    char* As = smem;
    char* Bs = smem + 16384;
    const int tid = threadIdx.x;
    const int lane = tid & 63;
    const int wave = tid >> 6;
    const int wm = wave >> 1, wn = wave & 1;
    const int lr = lane & 15, lg = lane >> 4;
    const int bm = blockIdx.x, bn = blockIdx.y;

    f32x4 acc[4][4] = {};

    const size_t a_row0 = (size_t)bm * 128;
    const size_t b_row0 = (size_t)bn * 128;

    for (int kt = 0; kt < K; kt += 64) {
        #pragma unroll
        for (int i = 0; i < 4; ++i) {
            const int id = tid + i * 256;
            const int row = id >> 3, c = id & 7;
            const int cs = (c ^ (row & 7)) * 8;  // inverse swizzle on source
            gload_lds16(A + (a_row0 + row) * K + kt + cs, As + id * 16);
            gload_lds16(Bt + (b_row0 + row) * K + kt + cs, Bs + id * 16);
        }
        __syncthreads();
        #pragma unroll
        for (int ks = 0; ks < 2; ++ks) {
            s16x8 af[4], bfr[4];
            #pragma unroll
            for (int mf = 0; mf < 4; ++mf) {
                const int row = wm * 64 + mf * 16 + lr;
                const int c = ks * 4 + lg;
                af[mf] = *reinterpret_cast<const s16x8*>(As + row * 128 + ((c ^ (row & 7)) * 16));
            }
            #pragma unroll
            for (int nf = 0; nf < 4; ++nf) {
                const int row = wn * 64 + nf * 16 + lr;
                const int c = ks * 4 + lg;
                bfr[nf] = *reinterpret_cast<const s16x8*>(Bs + row * 128 + ((c ^ (row & 7)) * 16));
            }
            #pragma unroll
            for (int mf = 0; mf < 4; ++mf)
                #pragma unroll
                for (int nf = 0; nf < 4; ++nf)
                    acc[mf][nf] = __builtin_amdgcn_mfma_f32_16x16x32_bf16(
                        af[mf], bfr[nf], acc[mf][nf], 0, 0, 0);
        }
        __syncthreads();
    }

    if (EPI == 3) {
        const int rq = bn / 6;                       // 0=q, 1=k, 2=v
        const int bb_ = bm >> 4;                     // batch index
        if (rq == 2) {
            // V: acc -> per-wave LDS tile (swizzled) -> coalesced Vt stores.
            char* Ws = smem + wave * 8192;
            #pragma unroll
            for (int nf = 0; nf < 4; ++nf) {
                const int cl = nf * 16 + lr;
                const int gn = bn * 128 + wn * 64 + nf * 16 + lr;
                const float bs = bias[gn];
                #pragma unroll
                for (int mf = 0; mf < 4; ++mf) {
                    unsigned short pk[4];
                    #pragma unroll
                    for (int i = 0; i < 4; ++i) pk[i] = f2bf(acc[mf][nf][i] + bs);
                    const int slot = (2 * mf + (lg >> 1)) ^ (cl & 7);
                    *reinterpret_cast<long long*>(Ws + cl * 128 + slot * 16 + (lg & 1) * 8) =
                        *reinterpret_cast<const long long*>(pk);
                }
            }
            __syncthreads();
            const int nb = (bm * 128 + wm * 64) & 2047;
            const int cb = (bn - 12) * 128 + wn * 64;
            #pragma unroll
            for (int r = 0; r < 8; ++r) {
                const int cl = r * 8 + (lane >> 3);
                const int j = lane & 7;
                const int4 vv = *reinterpret_cast<const int4*>(
                    Ws + cl * 128 + ((j ^ (cl & 7)) * 16));
                const int c = cb + cl;
                const int hh = c >> 6, dd = c & 63;
                *reinterpret_cast<int4*>(
                    Vt + ((size_t)(bb_ * 12 + hh) * 64 + dd) * 2048 + nb + j * 8) = vv;
            }
        } else {
            const int cb = bn * 128 - rq * 768 + wn * 64;
            bf16* dst = (rq == 0) ? Qb : Kb;
            #pragma unroll
            for (int mf = 0; mf < 4; ++mf) {
                #pragma unroll
                for (int i = 0; i < 4; ++i) {
                    const int gm = bm * 128 + wm * 64 + mf * 16 + 4 * lg + i;
                    const int n = gm & 2047;
                    const float msc = (rq == 0) ? (mask[gm] ? QSCALE : 0.f) : 1.f;
                    #pragma unroll
                    for (int nf = 0; nf < 4; ++nf) {
                        const int c = cb + nf * 16 + lr;
                        const int h = c >> 6, d = c & 63;
                        const int gn = bn * 128 + wn * 64 + nf * 16 + lr;
                        const float v = (acc[mf][nf][i] + bias[gn]) * msc;
                        dst[((size_t)(bb_ * 12 + h) * 2048 + n) * 64 + d] =
                            __float2bfloat16(v);
                    }
                }
            }
        }
        return;
    }

    #pragma unroll
    for (int mf = 0; mf < 4; ++mf) {
        #pragma unroll
        for (int i = 0; i < 4; ++i) {
            const int gm = bm * 128 + wm * 64 + mf * 16 + 4 * lg + i;
            #pragma unroll
            for (int nf = 0; nf < 4; ++nf) {
                const int gn = bn * 128 + wn * 64 + nf * 16 + lr;
                float v = acc[mf][nf][i] + bias[gn];
                if (EPI == 2) {
                    // gelu(x) = x - x/(1+e^{2y}), y = 0.79788456(x+0.044715x^3)
                    const float x3 = v * v * v;
                    const float z = fmaf(x3, 0.044715f, v) * 2.3022080f;
                    const float e = __builtin_amdgcn_exp2f(z);
                    v = v - v * __builtin_amdgcn_rcpf(1.f + e);
                }
                reinterpret_cast<bf16*>(outp)[(size_t)gm * N + gn] = __float2bfloat16(v);
            }
        }
    }
}

// ---------------------------------------------------------------------------
// GEMM 64x128 (grid-balanced variant for proj / FC2, both bias+resid->fp32).
// ---------------------------------------------------------------------------
__global__ __launch_bounds__(256) void gemm64(
    const bf16* __restrict__ A, const bf16* __restrict__ Bt,
    const float* __restrict__ bias, const float* __restrict__ resid,
    float* __restrict__ outp, int M, int N, int K)
{
    __shared__ alignas(16) char smem[24576];
    char* As = smem;             // 64 rows x 128B
    char* Bs = smem + 8192;      // 128 rows x 128B
    const int tid = threadIdx.x;
    const int lane = tid & 63;
    const int wn = tid >> 6;     // wave 0..3 -> N strip
    const int lr = lane & 15, lg = lane >> 4;
    const int bm = blockIdx.x, bn = blockIdx.y;

    f32x4 acc[4][2] = {};

    const size_t a_row0 = (size_t)bm * 64;
    const size_t b_row0 = (size_t)bn * 128;

    for (int kt = 0; kt < K; kt += 64) {
        #pragma unroll
        for (int i = 0; i < 2; ++i) {
            const int id = tid + i * 256;
            const int row = id >> 3, c = id & 7;
            const int cs = (c ^ (row & 7)) * 8;
            gload_lds16(A + (a_row0 + row) * K + kt + cs, As + id * 16);
        }
        #pragma unroll
        for (int i = 0; i < 4; ++i) {
            const int id = tid + i * 256;
            const int row = id >> 3, c = id & 7;
            const int cs = (c ^ (row & 7)) * 8;
            gload_lds16(Bt + (b_row0 + row) * K + kt + cs, Bs + id * 16);
        }
        __syncthreads();
        #pragma unroll
        for (int ks = 0; ks < 2; ++ks) {
            s16x8 af[4], bfr[2];
            #pragma unroll
            for (int mf = 0; mf < 4; ++mf) {
                const int row = mf * 16 + lr;
                const int c = ks * 4 + lg;
                af[mf] = *reinterpret_cast<const s16x8*>(As + row * 128 + ((c ^ (row & 7)) * 16));
            }
            #pragma unroll
            for (int nf = 0; nf < 2; ++nf) {
                const int row = wn * 32 + nf * 16 + lr;
                const int c = ks * 4 + lg;
                bfr[nf] = *reinterpret_cast<const s16x8*>(Bs + row * 128 + ((c ^ (row & 7)) * 16));
            }
            #pragma unroll
            for (int mf = 0; mf < 4; ++mf)
                #pragma unroll
                for (int nf = 0; nf < 2; ++nf)
                    acc[mf][nf] = __builtin_amdgcn_mfma_f32_16x16x32_bf16(
                        af[mf], bfr[nf], acc[mf][nf], 0, 0, 0);
        }
        __syncthreads();
    }

    #pragma unroll
    for (int mf = 0; mf < 4; ++mf) {
        #pragma unroll
        for (int i = 0; i < 4; ++i) {
            const int gm = bm * 64 + mf * 16 + 4 * lg + i;
            #pragma unroll
            for (int nf = 0; nf < 2; ++nf) {
                const int gn = bn * 128 + wn * 32 + nf * 16 + lr;
                outp[(size_t)gm * N + gn] =
                    acc[mf][nf][i] + bias[gn] + resid[(size_t)gm * N + gn];
            }
        }
    }
}

// ---------------------------------------------------------------------------
// Flash attention, round 11: 2-stage score pipeline (T15). Triple-buffered
// K/V (48KB, 3 blocks/CU); iter kb runs exp2/pack on the PREVIOUS tile's
// scores, then issues QK(kb+1) back-to-back with PV(kb) on the matrix pipe.
// exp2 never stalls on in-flight MFMA. Static-max softmax, ones-MFMA row sum.
// ---------------------------------------------------------------------------
__global__ __launch_bounds__(256, 3) void attn_kernel(
    const bf16* __restrict__ Qb, const bf16* __restrict__ Kb,
    const bf16* __restrict__ Vt, bf16* __restrict__ out)
{
    __shared__ alignas(16) char Ks[3][64 * 128];
    __shared__ alignas(16) char Vs[3][64 * 128];

    const int lin = blockIdx.x;            // 768 blocks
    const int xcd = lin & 7, slot = lin >> 3;
    const int pair = xcd * 6 + (slot >> 4);   // 0..47
    const int qb = slot & 15;
    const int b = pair / 12, h = pair % 12;

    const int tid = threadIdx.x, lane = tid & 63, wave = tid >> 6;
    const int lq = lane & 31;
    const int hi = lane >> 5;
    const size_t bh = (size_t)(b * 12 + h);
    const bf16* Kh = Kb + bh * 2048 * 64;
    const bf16* Vh = Vt + bh * 64 * 2048;
    const int q0w = qb * 128 + wave * 32;

    s16x8 qf[4];
    {
        const bf16* qp = Qb + (bh * 2048 + q0w + lq) * 64 + 8 * hi;
        #pragma unroll
        for (int ks = 0; ks < 4; ++ks)
            qf[ks] = *reinterpret_cast<const s16x8*>(qp + 16 * ks);
    }
    const int4 onesw = {0x3F803F80, 0x3F803F80, 0x3F803F80, 0x3F803F80};
    const s16x8 onesf = __builtin_bit_cast(s16x8, onesw);

    int sKoff0, sKoff1, dst0, dst1;
    size_t sVoff0, sVoff1;
    {
        const int id0 = tid;
        const int R0 = id0 >> 4;
        const int u0 = (id0 & 15) ^ (R0 & 15);
        const int rt0 = 2 * R0 + (u0 >> 3), s80 = (u0 & 7) * 8;
        sKoff0 = rt0 * 64 + s80;
        sVoff0 = (size_t)rt0 * 2048 + s80;
        dst0 = id0 * 16;
        const int id1 = tid + 256;
        const int R1 = id1 >> 4;
        const int u1 = (id1 & 15) ^ (R1 & 15);
        const int rt1 = 2 * R1 + (u1 >> 3), s81 = (u1 & 7) * 8;
        sKoff1 = rt1 * 64 + s81;
        sVoff1 = (size_t)rt1 * 2048 + s81;
        dst1 = id1 * 16;
    }

    const int rh = lq >> 1;
    const int m7 = rh & 7;
    const int rbase = rh * 256 + (((((lq & 1) << 3) ^ (rh & 8))) << 4);

    f32x16 o0 = {}, o1 = {};   // O^T accumulators: d 0..31 / 32..63
    f32x16 os = {};            // row-sum accumulator (all rows equal)

    #define STAGE(buf, kb)                                                    \
        do {                                                                  \
            gload_lds16(Kh + (kb) * 4096 + sKoff0, Ks[buf] + dst0);           \
            gload_lds16(Vh + (kb) * 64 + sVoff0, Vs[buf] + dst0);             \
            gload_lds16(Kh + (kb) * 4096 + sKoff1, Ks[buf] + dst1);           \
            gload_lds16(Vh + (kb) * 64 + sVoff1, Vs[buf] + dst1);             \
        } while (0)

    // compute S^T (both 32-key halves packed in one f32x16 pair) for buffer bf
    #define QKCOMP(stv0, stv1, bf)                                            \
        do {                                                                  \
            const char* Kc_ = Ks[bf] + rbase;                                 \
            __builtin_amdgcn_s_setprio(1);                                    \
            _Pragma("unroll")                                                 \
            for (int ks = 0; ks < 4; ++ks) {                                  \
                const int so_ = (((2 * ks + hi) ^ m7) << 4);                  \
                const s16x8 kf0_ = *reinterpret_cast<const s16x8*>(Kc_ + so_);\
                stv0 = __builtin_amdgcn_mfma_f32_32x32x16_bf16(kf0_, qf[ks], stv0, 0, 0, 0); \
                const s16x8 kf1_ = *reinterpret_cast<const s16x8*>(Kc_ + 4096 + so_); \
                stv1 = __builtin_amdgcn_mfma_f32_32x32x16_bf16(kf1_, qf[ks], stv1, 0, 0, 0); \
            }                                                                 \
            __builtin_amdgcn_s_setprio(0);                                    \
        } while (0)

    STAGE(0, 0);
    STAGE(1, 1);
    __syncthreads();

    f32x16 st0 = {}, st1 = {};
    QKCOMP(st0, st1, 0);

    for (int kb = 0; kb < 32; ++kb) {
        const int bV = kb % 3;
        if (kb < 30) STAGE((kb + 2) % 3, kb + 2);

        // ---- softmax of tile kb (scores computed an iteration ago) ----
        float p0[16], p1[16];
        #pragma unroll
        for (int r = 0; r < 16; ++r) {
            p0[r] = __builtin_amdgcn_exp2f(st0[r]);
            p1[r] = __builtin_amdgcn_exp2f(st1[r]);
        }
        const s16x8 pf00 = build_pfrag(p0[0], p0[1], p0[2], p0[3], p0[4], p0[5], p0[6], p0[7]);
        const s16x8 pf01 = build_pfrag(p0[8], p0[9], p0[10], p0[11], p0[12], p0[13], p0[14], p0[15]);
        const s16x8 pf10 = build_pfrag(p1[0], p1[1], p1[2], p1[3], p1[4], p1[5], p1[6], p1[7]);
        const s16x8 pf11 = build_pfrag(p1[8], p1[9], p1[10], p1[11], p1[12], p1[13], p1[14], p1[15]);

        // ---- QK for tile kb+1 (buffer published at last barrier) ----
        f32x16 nst0 = {}, nst1 = {};
        if (kb < 31) QKCOMP(nst0, nst1, (kb + 1) % 3);

        // ---- O^T += V^T(kb) * P^T ; l += 1 . P ----
        const char* Vc = Vs[bV] + rbase;
        __builtin_amdgcn_s_setprio(1);
        #pragma unroll
        for (int kf4 = 0; kf4 < 4; ++kf4) {
            const s16x8 pf = (kf4 == 0) ? pf00 : (kf4 == 1) ? pf01
                           : (kf4 == 2) ? pf10 : pf11;
            const int so = (((2 * kf4 + hi) ^ m7) << 4);
            const s16x8 vf0 = *reinterpret_cast<const s16x8*>(Vc + so);
            o0 = __builtin_amdgcn_mfma_f32_32x32x16_bf16(vf0, pf, o0, 0, 0, 0);
            const s16x8 vf1 = *reinterpret_cast<const s16x8*>(Vc + 4096 + so);
            o1 = __builtin_amdgcn_mfma_f32_32x32x16_bf16(vf1, pf, o1, 0, 0, 0);
            os = __builtin_amdgcn_mfma_f32_32x32x16_bf16(onesf, pf, os, 0, 0, 0);
        }
        __builtin_amdgcn_s_setprio(0);

        __syncthreads();
        st0 = nst0;
        st1 = nst1;
    }
    #undef STAGE
    #undef QKCOMP

    const float rl = 1.0f / os[0];   // l for q = lane&31 (all rows equal)
    bf16* orow = out + (size_t)(b * 2048 + q0w + lq) * 768 + h * 64;
    #pragma unroll
    for (int g = 0; g < 4; ++g) {
        unsigned short pk0[4], pk1[4];
        #pragma unroll
        for (int i = 0; i < 4; ++i) {
            pk0[i] = f2bf(o0[4 * g + i] * rl);
            pk1[i] = f2bf(o1[4 * g + i] * rl);
        }
        const int d0 = 8 * g + 4 * hi;
        *reinterpret_cast<int2*>(orow + d0) = *reinterpret_cast<const int2*>(pk0);
        *reinterpret_cast<int2*>(orow + 32 + d0) = *reinterpret_cast<const int2*>(pk1);
    }
}

// ---------------------------------------------------------------------------
// Launch
// ---------------------------------------------------------------------------
extern "C" void kernel_launch(void* const* d_in, const int* in_sizes, int n_in,
                              void* d_out, int out_size, void* d_ws, size_t ws_size,
                              hipStream_t stream)
{
    (void)in_sizes; (void)n_in; (void)out_size; (void)ws_size;
    const float* x      = (const float*)d_in[0];
    const int*   mask   = (const int*)d_in[1];
    const float* ln1_g  = (const float*)d_in[2];
    const float* ln1_b  = (const float*)d_in[3];
    const float* qkv_w  = (const float*)d_in[4];
    const float* qkv_b  = (const float*)d_in[5];
    const float* proj_w = (const float*)d_in[6];
    const float* proj_b = (const float*)d_in[7];
    const float* ln2_g  = (const float*)d_in[8];
    const float* ln2_b  = (const float*)d_in[9];
    const float* fc1_w  = (const float*)d_in[10];
    const float* fc1_b  = (const float*)d_in[11];
    const float* fc2_w  = (const float*)d_in[12];
    const float* fc2_b  = (const float*)d_in[13];
    float* out = (float*)d_out;
    char* ws = (char*)d_ws;

    bf16*  Wt_qkv  = (bf16*)(ws + 0);          // [2304][768]
    bf16*  Wt_proj = (bf16*)(ws + 3538944);    // [768][768]
    bf16*  Wt_fc1  = (bf16*)(ws + 4718592);    // [3072][768]
    bf16*  Wt_fc2  = (bf16*)(ws + 9437184);    // [768][3072]
    bf16*  hbuf    = (bf16*)(ws + 14155776);   // [8192][768]
    bf16*  attnout = (bf16*)(ws + 64487424);   // [8192][768]
    float* x1      = (float*)(ws + 77070336);  // [8192][768]
    bf16*  h2      = (bf16*)(ws + 102236160);  // [8192][768]
    bf16*  a1      = (bf16*)(ws + 114819072);  // [8192][3072] (FC1 out)
    bf16*  Qb      = (bf16*)(ws + 114819072);  // overlay: [4][12][2048][64]
    bf16*  Kb      = (bf16*)(ws + 127401984);
    bf16*  Vt      = (bf16*)(ws + 139984896);

    transpose_all<<<6912, dim3(32, 8), 0, stream>>>(
        qkv_w, proj_w, fc1_w, fc2_w, Wt_qkv, Wt_proj, Wt_fc1, Wt_fc2);

    ln_kernel<<<8192, 256, 0, stream>>>(x, ln1_g, ln1_b, hbuf);
    gemm_bt<3><<<dim3(64, 18), 256, 0, stream>>>(hbuf, Wt_qkv, qkv_b, nullptr,
                                                 mask, Qb, Kb, Vt, 8192, 2304, 768);
    attn_kernel<<<768, 256, 0, stream>>>(Qb, Kb, Vt, attnout);
    gemm64<<<dim3(128, 6), 256, 0, stream>>>(attnout, Wt_proj, proj_b, x, x1,
                                             8192, 768, 768);
    ln_kernel<<<8192, 256, 0, stream>>>(x1, ln2_g, ln2_b, h2);
    gemm_bt<2><<<dim3(64, 24), 256, 0, stream>>>(h2, Wt_fc1, fc1_b, a1,
                                                 nullptr, nullptr, nullptr, nullptr, 8192, 3072, 768);
    gemm64<<<dim3(128, 6), 256, 0, stream>>>(a1, Wt_fc2, fc2_b, x1, out,
                                             8192, 768, 3072);
}

// Round 12
// 249.538 us; speedup vs baseline: 1.0144x; 1.0144x over previous
//
#include <hip/hip_runtime.h>
#include <hip/hip_bf16.h>
#include <math.h>

using bf16 = __hip_bfloat16;
typedef short s16x8 __attribute__((ext_vector_type(8)));
typedef float f32x4 __attribute__((ext_vector_type(4)));
typedef float f32x16 __attribute__((ext_vector_type(16)));

#define LOG2E 1.4426950408889634f
// Q pre-scale: D^-0.5 * log2(e) so QK^T scores land directly in log2 domain.
#define QSCALE 0.18033688f

__device__ inline unsigned short f2bf(float f) {
    bf16 h = __float2bfloat16(f);
    return __builtin_bit_cast(unsigned short, h);
}

// async global->LDS, 16B per lane. Dest must be wave-linear (base + lane*16).
__device__ inline void gload_lds16(const void* g, void* l) {
    __builtin_amdgcn_global_load_lds(
        (const __attribute__((address_space(1))) void*)g,
        (__attribute__((address_space(3))) void*)l, 16, 0, 0);
}

__device__ inline unsigned cvtpk(float lo, float hi) {
    unsigned r;
    asm("v_cvt_pk_bf16_f32 %0, %1, %2" : "=v"(r) : "v"(lo), "v"(hi));
    return r;
}

// Build PV B-operand fragment from 8 in-lane P values (verified mapping).
__device__ inline s16x8 build_pfrag(float p0, float p1, float p2, float p3,
                                    float p4, float p5, float p6, float p7) {
    unsigned w01 = cvtpk(p0, p1);
    unsigned w23 = cvtpk(p2, p3);
    unsigned w45 = cvtpk(p4, p5);
    unsigned w67 = cvtpk(p6, p7);
    asm volatile("v_permlane32_swap_b32 %0, %1" : "+v"(w01), "+v"(w45));
    asm volatile("v_permlane32_swap_b32 %0, %1" : "+v"(w23), "+v"(w67));
    int4 t = {(int)w01, (int)w23, (int)w45, (int)w67};
    return __builtin_bit_cast(s16x8, t);
}

// ---------------------------------------------------------------------------
// Merged weight prep: all four W -> W^T bf16 in ONE launch.
// ---------------------------------------------------------------------------
__global__ __launch_bounds__(256) void transpose_all(
    const float* __restrict__ qkv_w, const float* __restrict__ proj_w,
    const float* __restrict__ fc1_w, const float* __restrict__ fc2_w,
    bf16* __restrict__ Wqkv, bf16* __restrict__ Wproj,
    bf16* __restrict__ Wfc1, bf16* __restrict__ Wfc2)
{
    int t = blockIdx.x;
    const float* in;
    bf16* out;
    int K, N, xt;
    if (t < 1728)      { in = qkv_w;  out = Wqkv;  K = 768;  N = 2304; xt = 72; }
    else if (t < 2304) { in = proj_w; out = Wproj; K = 768;  N = 768;  xt = 24; t -= 1728; }
    else if (t < 4608) { in = fc1_w;  out = Wfc1;  K = 768;  N = 3072; xt = 96; t -= 2304; }
    else               { in = fc2_w;  out = Wfc2;  K = 3072; N = 768;  xt = 24; t -= 4608; }
    const int bx = (t % xt) * 32;  // n
    const int by = (t / xt) * 32;  // k

    __shared__ float tile[32][33];
    const int tx = threadIdx.x, ty = threadIdx.y;  // 32 x 8
    #pragma unroll
    for (int i = 0; i < 32; i += 8)
        tile[ty + i][tx] = in[(size_t)(by + ty + i) * N + bx + tx];
    __syncthreads();
    #pragma unroll
    for (int i = 0; i < 32; i += 8)
        out[(size_t)(bx + ty + i) * K + by + tx] = __float2bfloat16(tile[tx][ty + i]);
}

// ---------------------------------------------------------------------------
// LayerNorm over C=768, fp32 in -> bf16 out. ONE WAVE PER ROW (4 rows/block):
// float4 loads (16B/lane, coalesced), wave-local shfl reduce, no LDS/barrier.
// ---------------------------------------------------------------------------
__global__ __launch_bounds__(256) void ln_kernel(
    const float* __restrict__ x, const float* __restrict__ g,
    const float* __restrict__ bb, bf16* __restrict__ out)
{
    const int wave = threadIdx.x >> 6, lane = threadIdx.x & 63;
    const int row = blockIdx.x * 4 + wave;
    const float* xr = x + (size_t)row * 768;
    float4 v[3];
    float s = 0.f, s2 = 0.f;
    #pragma unroll
    for (int i = 0; i < 3; ++i) {
        v[i] = *reinterpret_cast<const float4*>(xr + (lane + 64 * i) * 4);
        s += (v[i].x + v[i].y) + (v[i].z + v[i].w);
        s2 += (v[i].x * v[i].x + v[i].y * v[i].y) + (v[i].z * v[i].z + v[i].w * v[i].w);
    }
    #pragma unroll
    for (int off = 1; off < 64; off <<= 1) {
        s += __shfl_xor(s, off);
        s2 += __shfl_xor(s2, off);
    }
    const float mu = s * (1.f / 768.f);
    const float var = s2 * (1.f / 768.f) - mu * mu;
    const float r = rsqrtf(var + 1e-6f);
    bf16* orow = out + (size_t)row * 768;
    #pragma unroll
    for (int i = 0; i < 3; ++i) {
        const int col = (lane + 64 * i) * 4;
        const float4 gg = *reinterpret_cast<const float4*>(g + col);
        const float4 bv = *reinterpret_cast<const float4*>(bb + col);
        unsigned short pk[4];
        pk[0] = f2bf((v[i].x - mu) * r * gg.x + bv.x);
        pk[1] = f2bf((v[i].y - mu) * r * gg.y + bv.y);
        pk[2] = f2bf((v[i].z - mu) * r * gg.z + bv.z);
        pk[3] = f2bf((v[i].w - mu) * r * gg.w + bv.w);
        *reinterpret_cast<int2*>(orow + col) = *reinterpret_cast<const int2*>(pk);
    }
}

// ---------------------------------------------------------------------------
// GEMM 128x128 (known-good): out = A @ Bt^T + bias (+ gelu / QKV scatter).
// EPI: 2 = bias+gelu -> bf16 ; 3 = fused QKV scatter.
// ---------------------------------------------------------------------------
template <int EPI>
__global__ __launch_bounds__(256) void gemm_bt(
    const bf16* __restrict__ A, const bf16* __restrict__ Bt,
    const float* __restrict__ bias,
    void* __restrict__ outp, const int* __restrict__ mask,
    bf16* __restrict__ Qb, bf16* __restrict__ Kb, bf16* __restrict__ Vt,
    int M, int N, int K)
{
    __shared__ alignas(16) char smem[32768];
    char* As = smem;
    char* Bs = smem + 16384;
    const int tid = threadIdx.x;
    const int lane = tid & 63;
    const int wave = tid >> 6;
    const int wm = wave >> 1, wn = wave & 1;
    const int lr = lane & 15, lg = lane >> 4;
    const int bm = blockIdx.x, bn = blockIdx.y;

    f32x4 acc[4][4] = {};

    const size_t a_row0 = (size_t)bm * 128;
    const size_t b_row0 = (size_t)bn * 128;

    for (int kt = 0; kt < K; kt += 64) {
        #pragma unroll
        for (int i = 0; i < 4; ++i) {
            const int id = tid + i * 256;
            const int row = id >> 3, c = id & 7;
            const int cs = (c ^ (row & 7)) * 8;  // inverse swizzle on source
            gload_lds16(A + (a_row0 + row) * K + kt + cs, As + id * 16);
            gload_lds16(Bt + (b_row0 + row) * K + kt + cs, Bs + id * 16);
        }
        __syncthreads();
        #pragma unroll
        for (int ks = 0; ks < 2; ++ks) {
            s16x8 af[4], bfr[4];
            #pragma unroll
            for (int mf = 0; mf < 4; ++mf) {
                const int row = wm * 64 + mf * 16 + lr;
                const int c = ks * 4 + lg;
                af[mf] = *reinterpret_cast<const s16x8*>(As + row * 128 + ((c ^ (row & 7)) * 16));
            }
            #pragma unroll
            for (int nf = 0; nf < 4; ++nf) {
                const int row = wn * 64 + nf * 16 + lr;
                const int c = ks * 4 + lg;
                bfr[nf] = *reinterpret_cast<const s16x8*>(Bs + row * 128 + ((c ^ (row & 7)) * 16));
            }
            #pragma unroll
            for (int mf = 0; mf < 4; ++mf)
                #pragma unroll
                for (int nf = 0; nf < 4; ++nf)
                    acc[mf][nf] = __builtin_amdgcn_mfma_f32_16x16x32_bf16(
                        af[mf], bfr[nf], acc[mf][nf], 0, 0, 0);
        }
        __syncthreads();
    }

    if (EPI == 3) {
        const int rq = bn / 6;                       // 0=q, 1=k, 2=v
        const int bb_ = bm >> 4;                     // batch index
        if (rq == 2) {
            // V: acc -> per-wave LDS tile (swizzled) -> coalesced Vt stores.
            char* Ws = smem + wave * 8192;
            #pragma unroll
            for (int nf = 0; nf < 4; ++nf) {
                const int cl = nf * 16 + lr;
                const int gn = bn * 128 + wn * 64 + nf * 16 + lr;
                const float bs = bias[gn];
                #pragma unroll
                for (int mf = 0; mf < 4; ++mf) {
                    unsigned short pk[4];
                    #pragma unroll
                    for (int i = 0; i < 4; ++i) pk[i] = f2bf(acc[mf][nf][i] + bs);
                    const int slot = (2 * mf + (lg >> 1)) ^ (cl & 7);
                    *reinterpret_cast<long long*>(Ws + cl * 128 + slot * 16 + (lg & 1) * 8) =
                        *reinterpret_cast<const long long*>(pk);
                }
            }
            __syncthreads();
            const int nb = (bm * 128 + wm * 64) & 2047;
            const int cb = (bn - 12) * 128 + wn * 64;
            #pragma unroll
            for (int r = 0; r < 8; ++r) {
                const int cl = r * 8 + (lane >> 3);
                const int j = lane & 7;
                const int4 vv = *reinterpret_cast<const int4*>(
                    Ws + cl * 128 + ((j ^ (cl & 7)) * 16));
                const int c = cb + cl;
                const int hh = c >> 6, dd = c & 63;
                *reinterpret_cast<int4*>(
                    Vt + ((size_t)(bb_ * 12 + hh) * 64 + dd) * 2048 + nb + j * 8) = vv;
            }
        } else {
            const int cb = bn * 128 - rq * 768 + wn * 64;
            bf16* dst = (rq == 0) ? Qb : Kb;
            #pragma unroll
            for (int mf = 0; mf < 4; ++mf) {
                #pragma unroll
                for (int i = 0; i < 4; ++i) {
                    const int gm = bm * 128 + wm * 64 + mf * 16 + 4 * lg + i;
                    const int n = gm & 2047;
                    const float msc = (rq == 0) ? (mask[gm] ? QSCALE : 0.f) : 1.f;
                    #pragma unroll
                    for (int nf = 0; nf < 4; ++nf) {
                        const int c = cb + nf * 16 + lr;
                        const int h = c >> 6, d = c & 63;
                        const int gn = bn * 128 + wn * 64 + nf * 16 + lr;
                        const float v = (acc[mf][nf][i] + bias[gn]) * msc;
                        dst[((size_t)(bb_ * 12 + h) * 2048 + n) * 64 + d] =
                            __float2bfloat16(v);
                    }
                }
            }
        }
        return;
    }

    #pragma unroll
    for (int mf = 0; mf < 4; ++mf) {
        #pragma unroll
        for (int i = 0; i < 4; ++i) {
            const int gm = bm * 128 + wm * 64 + mf * 16 + 4 * lg + i;
            #pragma unroll
            for (int nf = 0; nf < 4; ++nf) {
                const int gn = bn * 128 + wn * 64 + nf * 16 + lr;
                float v = acc[mf][nf][i] + bias[gn];
                if (EPI == 2) {
                    // gelu(x) = x - x/(1+e^{2y}), y = 0.79788456(x+0.044715x^3)
                    const float x3 = v * v * v;
                    const float z = fmaf(x3, 0.044715f, v) * 2.3022080f;
                    const float e = __builtin_amdgcn_exp2f(z);
                    v = v - v * __builtin_amdgcn_rcpf(1.f + e);
                }
                reinterpret_cast<bf16*>(outp)[(size_t)gm * N + gn] = __float2bfloat16(v);
            }
        }
    }
}

// ---------------------------------------------------------------------------
// GEMM 64x128 (grid-balanced variant for proj / FC2, both bias+resid->fp32).
// ---------------------------------------------------------------------------
__global__ __launch_bounds__(256) void gemm64(
    const bf16* __restrict__ A, const bf16* __restrict__ Bt,
    const float* __restrict__ bias, const float* __restrict__ resid,
    float* __restrict__ outp, int M, int N, int K)
{
    __shared__ alignas(16) char smem[24576];
    char* As = smem;             // 64 rows x 128B
    char* Bs = smem + 8192;      // 128 rows x 128B
    const int tid = threadIdx.x;
    const int lane = tid & 63;
    const int wn = tid >> 6;     // wave 0..3 -> N strip
    const int lr = lane & 15, lg = lane >> 4;
    const int bm = blockIdx.x, bn = blockIdx.y;

    f32x4 acc[4][2] = {};

    const size_t a_row0 = (size_t)bm * 64;
    const size_t b_row0 = (size_t)bn * 128;

    for (int kt = 0; kt < K; kt += 64) {
        #pragma unroll
        for (int i = 0; i < 2; ++i) {
            const int id = tid + i * 256;
            const int row = id >> 3, c = id & 7;
            const int cs = (c ^ (row & 7)) * 8;
            gload_lds16(A + (a_row0 + row) * K + kt + cs, As + id * 16);
        }
        #pragma unroll
        for (int i = 0; i < 4; ++i) {
            const int id = tid + i * 256;
            const int row = id >> 3, c = id & 7;
            const int cs = (c ^ (row & 7)) * 8;
            gload_lds16(Bt + (b_row0 + row) * K + kt + cs, Bs + id * 16);
        }
        __syncthreads();
        #pragma unroll
        for (int ks = 0; ks < 2; ++ks) {
            s16x8 af[4], bfr[2];
            #pragma unroll
            for (int mf = 0; mf < 4; ++mf) {
                const int row = mf * 16 + lr;
                const int c = ks * 4 + lg;
                af[mf] = *reinterpret_cast<const s16x8*>(As + row * 128 + ((c ^ (row & 7)) * 16));
            }
            #pragma unroll
            for (int nf = 0; nf < 2; ++nf) {
                const int row = wn * 32 + nf * 16 + lr;
                const int c = ks * 4 + lg;
                bfr[nf] = *reinterpret_cast<const s16x8*>(Bs + row * 128 + ((c ^ (row & 7)) * 16));
            }
            #pragma unroll
            for (int mf = 0; mf < 4; ++mf)
                #pragma unroll
                for (int nf = 0; nf < 2; ++nf)
                    acc[mf][nf] = __builtin_amdgcn_mfma_f32_16x16x32_bf16(
                        af[mf], bfr[nf], acc[mf][nf], 0, 0, 0);
        }
        __syncthreads();
    }

    #pragma unroll
    for (int mf = 0; mf < 4; ++mf) {
        #pragma unroll
        for (int i = 0; i < 4; ++i) {
            const int gm = bm * 64 + mf * 16 + 4 * lg + i;
            #pragma unroll
            for (int nf = 0; nf < 2; ++nf) {
                const int gn = bn * 128 + wn * 32 + nf * 16 + lr;
                outp[(size_t)gm * N + gn] =
                    acc[mf][nf][i] + bias[gn] + resid[(size_t)gm * N + gn];
            }
        }
    }
}

// ---------------------------------------------------------------------------
// Flash attention (R10 structure, T15 reverted): static-max softmax
// (p = exp2(st) directly), ones-MFMA row sum, dbuf staging, XCD remap,
// conflict-free 2-row-interleaved LDS swizzle.
// ---------------------------------------------------------------------------
__global__ __launch_bounds__(256, 3) void attn_kernel(
    const bf16* __restrict__ Qb, const bf16* __restrict__ Kb,
    const bf16* __restrict__ Vt, bf16* __restrict__ out)
{
    __shared__ alignas(16) char Ks[2][64 * 128];
    __shared__ alignas(16) char Vs[2][64 * 128];

    const int lin = blockIdx.x;            // 768 blocks
    const int xcd = lin & 7, slot = lin >> 3;
    const int pair = xcd * 6 + (slot >> 4);   // 0..47
    const int qb = slot & 15;
    const int b = pair / 12, h = pair % 12;

    const int tid = threadIdx.x, lane = tid & 63, wave = tid >> 6;
    const int lq = lane & 31;
    const int hi = lane >> 5;
    const size_t bh = (size_t)(b * 12 + h);
    const bf16* Kh = Kb + bh * 2048 * 64;
    const bf16* Vh = Vt + bh * 64 * 2048;
    const int q0w = qb * 128 + wave * 32;

    s16x8 qf[4];
    {
        const bf16* qp = Qb + (bh * 2048 + q0w + lq) * 64 + 8 * hi;
        #pragma unroll
        for (int ks = 0; ks < 4; ++ks)
            qf[ks] = *reinterpret_cast<const s16x8*>(qp + 16 * ks);
    }
    const int4 onesw = {0x3F803F80, 0x3F803F80, 0x3F803F80, 0x3F803F80};
    const s16x8 onesf = __builtin_bit_cast(s16x8, onesw);

    int sKoff0, sKoff1, dst0, dst1;
    size_t sVoff0, sVoff1;
    {
        const int id0 = tid;
        const int R0 = id0 >> 4;
        const int u0 = (id0 & 15) ^ (R0 & 15);
        const int rt0 = 2 * R0 + (u0 >> 3), s80 = (u0 & 7) * 8;
        sKoff0 = rt0 * 64 + s80;
        sVoff0 = (size_t)rt0 * 2048 + s80;
        dst0 = id0 * 16;
        const int id1 = tid + 256;
        const int R1 = id1 >> 4;
        const int u1 = (id1 & 15) ^ (R1 & 15);
        const int rt1 = 2 * R1 + (u1 >> 3), s81 = (u1 & 7) * 8;
        sKoff1 = rt1 * 64 + s81;
        sVoff1 = (size_t)rt1 * 2048 + s81;
        dst1 = id1 * 16;
    }

    const int rh = lq >> 1;
    const int m7 = rh & 7;
    const int rbase = rh * 256 + (((((lq & 1) << 3) ^ (rh & 8))) << 4);

    f32x16 o0 = {}, o1 = {};   // O^T accumulators: d 0..31 / 32..63
    f32x16 os = {};            // row-sum accumulator (all rows equal)

    #define STAGE(buf, kb)                                                    \
        do {                                                                  \
            gload_lds16(Kh + (kb) * 4096 + sKoff0, Ks[buf] + dst0);           \
            gload_lds16(Vh + (kb) * 64 + sVoff0, Vs[buf] + dst0);             \
            gload_lds16(Kh + (kb) * 4096 + sKoff1, Ks[buf] + dst1);           \
            gload_lds16(Vh + (kb) * 64 + sVoff1, Vs[buf] + dst1);             \
        } while (0)

    STAGE(0, 0);
    __syncthreads();
    int cur = 0;

    for (int kb = 0; kb < 32; ++kb) {
        if (kb < 31) STAGE(cur ^ 1, kb + 1);
        const char* Kc = Ks[cur] + rbase;
        const char* Vc = Vs[cur] + rbase;

        // ---- S^T (log2 domain) for both 32-key subtiles: 8 MFMAs ----
        f32x16 st0 = {}, st1 = {};
        __builtin_amdgcn_s_setprio(1);
        #pragma unroll
        for (int ks = 0; ks < 4; ++ks) {
            const int so = (((2 * ks + hi) ^ m7) << 4);
            const s16x8 kf0 = *reinterpret_cast<const s16x8*>(Kc + so);
            st0 = __builtin_amdgcn_mfma_f32_32x32x16_bf16(kf0, qf[ks], st0, 0, 0, 0);
            const s16x8 kf1 = *reinterpret_cast<const s16x8*>(Kc + 4096 + so);
            st1 = __builtin_amdgcn_mfma_f32_32x32x16_bf16(kf1, qf[ks], st1, 0, 0, 0);
        }
        __builtin_amdgcn_s_setprio(0);

        // ---- static-max softmax: p = exp2(st) ----
        float p0[16], p1[16];
        #pragma unroll
        for (int r = 0; r < 16; ++r) {
            p0[r] = __builtin_amdgcn_exp2f(st0[r]);
            p1[r] = __builtin_amdgcn_exp2f(st1[r]);
        }

        // ---- P^T B-frags (4 x 16 keys) ----
        const s16x8 pf00 = build_pfrag(p0[0], p0[1], p0[2], p0[3], p0[4], p0[5], p0[6], p0[7]);
        const s16x8 pf01 = build_pfrag(p0[8], p0[9], p0[10], p0[11], p0[12], p0[13], p0[14], p0[15]);
        const s16x8 pf10 = build_pfrag(p1[0], p1[1], p1[2], p1[3], p1[4], p1[5], p1[6], p1[7]);
        const s16x8 pf11 = build_pfrag(p1[8], p1[9], p1[10], p1[11], p1[12], p1[13], p1[14], p1[15]);

        // ---- O^T += V^T * P^T ; l += 1 . P (matrix pipe) ----
        __builtin_amdgcn_s_setprio(1);
        #pragma unroll
        for (int kf4 = 0; kf4 < 4; ++kf4) {
            const s16x8 pf = (kf4 == 0) ? pf00 : (kf4 == 1) ? pf01
                           : (kf4 == 2) ? pf10 : pf11;
            const int so = (((2 * kf4 + hi) ^ m7) << 4);
            const s16x8 vf0 = *reinterpret_cast<const s16x8*>(Vc + so);
            o0 = __builtin_amdgcn_mfma_f32_32x32x16_bf16(vf0, pf, o0, 0, 0, 0);
            const s16x8 vf1 = *reinterpret_cast<const s16x8*>(Vc + 4096 + so);
            o1 = __builtin_amdgcn_mfma_f32_32x32x16_bf16(vf1, pf, o1, 0, 0, 0);
            os = __builtin_amdgcn_mfma_f32_32x32x16_bf16(onesf, pf, os, 0, 0, 0);
        }
        __builtin_amdgcn_s_setprio(0);

        __syncthreads();
        cur ^= 1;
    }
    #undef STAGE

    const float rl = 1.0f / os[0];   // l for q = lane&31 (all rows equal)
    bf16* orow = out + (size_t)(b * 2048 + q0w + lq) * 768 + h * 64;
    #pragma unroll
    for (int g = 0; g < 4; ++g) {
        unsigned short pk0[4], pk1[4];
        #pragma unroll
        for (int i = 0; i < 4; ++i) {
            pk0[i] = f2bf(o0[4 * g + i] * rl);
            pk1[i] = f2bf(o1[4 * g + i] * rl);
        }
        const int d0 = 8 * g + 4 * hi;
        *reinterpret_cast<int2*>(orow + d0) = *reinterpret_cast<const int2*>(pk0);
        *reinterpret_cast<int2*>(orow + 32 + d0) = *reinterpret_cast<const int2*>(pk1);
    }
}

// ---------------------------------------------------------------------------
// Launch
// ---------------------------------------------------------------------------
extern "C" void kernel_launch(void* const* d_in, const int* in_sizes, int n_in,
                              void* d_out, int out_size, void* d_ws, size_t ws_size,
                              hipStream_t stream)
{
    (void)in_sizes; (void)n_in; (void)out_size; (void)ws_size;
    const float* x      = (const float*)d_in[0];
    const int*   mask   = (const int*)d_in[1];
    const float* ln1_g  = (const float*)d_in[2];
    const float* ln1_b  = (const float*)d_in[3];
    const float* qkv_w  = (const float*)d_in[4];
    const float* qkv_b  = (const float*)d_in[5];
    const float* proj_w = (const float*)d_in[6];
    const float* proj_b = (const float*)d_in[7];
    const float* ln2_g  = (const float*)d_in[8];
    const float* ln2_b  = (const float*)d_in[9];
    const float* fc1_w  = (const float*)d_in[10];
    const float* fc1_b  = (const float*)d_in[11];
    const float* fc2_w  = (const float*)d_in[12];
    const float* fc2_b  = (const float*)d_in[13];
    float* out = (float*)d_out;
    char* ws = (char*)d_ws;

    bf16*  Wt_qkv  = (bf16*)(ws + 0);          // [2304][768]
    bf16*  Wt_proj = (bf16*)(ws + 3538944);    // [768][768]
    bf16*  Wt_fc1  = (bf16*)(ws + 4718592);    // [3072][768]
    bf16*  Wt_fc2  = (bf16*)(ws + 9437184);    // [768][3072]
    bf16*  hbuf    = (bf16*)(ws + 14155776);   // [8192][768]
    bf16*  attnout = (bf16*)(ws + 64487424);   // [8192][768]
    float* x1      = (float*)(ws + 77070336);  // [8192][768]
    bf16*  h2      = (bf16*)(ws + 102236160);  // [8192][768]
    bf16*  a1      = (bf16*)(ws + 114819072);  // [8192][3072] (FC1 out)
    bf16*  Qb      = (bf16*)(ws + 114819072);  // overlay: [4][12][2048][64]
    bf16*  Kb      = (bf16*)(ws + 127401984);
    bf16*  Vt      = (bf16*)(ws + 139984896);

    transpose_all<<<6912, dim3(32, 8), 0, stream>>>(
        qkv_w, proj_w, fc1_w, fc2_w, Wt_qkv, Wt_proj, Wt_fc1, Wt_fc2);

    ln_kernel<<<2048, 256, 0, stream>>>(x, ln1_g, ln1_b, hbuf);
    gemm_bt<3><<<dim3(64, 18), 256, 0, stream>>>(hbuf, Wt_qkv, qkv_b, nullptr,
                                                 mask, Qb, Kb, Vt, 8192, 2304, 768);
    attn_kernel<<<768, 256, 0, stream>>>(Qb, Kb, Vt, attnout);
    gemm64<<<dim3(128, 6), 256, 0, stream>>>(attnout, Wt_proj, proj_b, x, x1,
                                             8192, 768, 768);
    ln_kernel<<<2048, 256, 0, stream>>>(x1, ln2_g, ln2_b, h2);
    gemm_bt<2><<<dim3(64, 24), 256, 0, stream>>>(h2, Wt_fc1, fc1_b, a1,
                                                 nullptr, nullptr, nullptr, nullptr, 8192, 3072, 768);
    gemm64<<<dim3(128, 6), 256, 0, stream>>>(a1, Wt_fc2, fc2_b, x1, out,
                                             8192, 768, 3072);
}

// Round 13
// 241.436 us; speedup vs baseline: 1.0484x; 1.0336x over previous
//
#include <hip/hip_runtime.h>
#include <hip/hip_bf16.h>
#include <math.h>

using bf16 = __hip_bfloat16;
typedef short s16x8 __attribute__((ext_vector_type(8)));
typedef float f32x4 __attribute__((ext_vector_type(4)));
typedef float f32x16 __attribute__((ext_vector_type(16)));

#define LOG2E 1.4426950408889634f
// Q pre-scale: D^-0.5 * log2(e) so QK^T scores land directly in log2 domain.
#define QSCALE 0.18033688f

__device__ inline unsigned short f2bf(float f) {
    bf16 h = __float2bfloat16(f);
    return __builtin_bit_cast(unsigned short, h);
}

// async global->LDS, 16B per lane. Dest must be wave-linear (base + lane*16).
__device__ inline void gload_lds16(const void* g, void* l) {
    __builtin_amdgcn_global_load_lds(
        (const __attribute__((address_space(1))) void*)g,
        (__attribute__((address_space(3))) void*)l, 16, 0, 0);
}

__device__ inline unsigned cvtpk(float lo, float hi) {
    unsigned r;
    asm("v_cvt_pk_bf16_f32 %0, %1, %2" : "=v"(r) : "v"(lo), "v"(hi));
    return r;
}

// Build PV B-operand fragment from 8 in-lane P values (verified mapping).
__device__ inline s16x8 build_pfrag(float p0, float p1, float p2, float p3,
                                    float p4, float p5, float p6, float p7) {
    unsigned w01 = cvtpk(p0, p1);
    unsigned w23 = cvtpk(p2, p3);
    unsigned w45 = cvtpk(p4, p5);
    unsigned w67 = cvtpk(p6, p7);
    asm volatile("v_permlane32_swap_b32 %0, %1" : "+v"(w01), "+v"(w45));
    asm volatile("v_permlane32_swap_b32 %0, %1" : "+v"(w23), "+v"(w67));
    int4 t = {(int)w01, (int)w23, (int)w45, (int)w67};
    return __builtin_bit_cast(s16x8, t);
}

// ---------------------------------------------------------------------------
// Merged weight prep: all four W -> W^T bf16 in ONE launch.
// ---------------------------------------------------------------------------
__global__ __launch_bounds__(256) void transpose_all(
    const float* __restrict__ qkv_w, const float* __restrict__ proj_w,
    const float* __restrict__ fc1_w, const float* __restrict__ fc2_w,
    bf16* __restrict__ Wqkv, bf16* __restrict__ Wproj,
    bf16* __restrict__ Wfc1, bf16* __restrict__ Wfc2)
{
    int t = blockIdx.x;
    const float* in;
    bf16* out;
    int K, N, xt;
    if (t < 1728)      { in = qkv_w;  out = Wqkv;  K = 768;  N = 2304; xt = 72; }
    else if (t < 2304) { in = proj_w; out = Wproj; K = 768;  N = 768;  xt = 24; t -= 1728; }
    else if (t < 4608) { in = fc1_w;  out = Wfc1;  K = 768;  N = 3072; xt = 96; t -= 2304; }
    else               { in = fc2_w;  out = Wfc2;  K = 3072; N = 768;  xt = 24; t -= 4608; }
    const int bx = (t % xt) * 32;  // n
    const int by = (t / xt) * 32;  // k

    __shared__ float tile[32][33];
    const int tx = threadIdx.x, ty = threadIdx.y;  // 32 x 8
    #pragma unroll
    for (int i = 0; i < 32; i += 8)
        tile[ty + i][tx] = in[(size_t)(by + ty + i) * N + bx + tx];
    __syncthreads();
    #pragma unroll
    for (int i = 0; i < 32; i += 8)
        out[(size_t)(bx + ty + i) * K + by + tx] = __float2bfloat16(tile[tx][ty + i]);
}

// ---------------------------------------------------------------------------
// LayerNorm over C=768, fp32 in -> bf16 out. ONE WAVE PER ROW (4 rows/block).
// ---------------------------------------------------------------------------
__global__ __launch_bounds__(256) void ln_kernel(
    const float* __restrict__ x, const float* __restrict__ g,
    const float* __restrict__ bb, bf16* __restrict__ out)
{
    const int wave = threadIdx.x >> 6, lane = threadIdx.x & 63;
    const int row = blockIdx.x * 4 + wave;
    const float* xr = x + (size_t)row * 768;
    float4 v[3];
    float s = 0.f, s2 = 0.f;
    #pragma unroll
    for (int i = 0; i < 3; ++i) {
        v[i] = *reinterpret_cast<const float4*>(xr + (lane + 64 * i) * 4);
        s += (v[i].x + v[i].y) + (v[i].z + v[i].w);
        s2 += (v[i].x * v[i].x + v[i].y * v[i].y) + (v[i].z * v[i].z + v[i].w * v[i].w);
    }
    #pragma unroll
    for (int off = 1; off < 64; off <<= 1) {
        s += __shfl_xor(s, off);
        s2 += __shfl_xor(s2, off);
    }
    const float mu = s * (1.f / 768.f);
    const float var = s2 * (1.f / 768.f) - mu * mu;
    const float r = rsqrtf(var + 1e-6f);
    bf16* orow = out + (size_t)row * 768;
    #pragma unroll
    for (int i = 0; i < 3; ++i) {
        const int col = (lane + 64 * i) * 4;
        const float4 gg = *reinterpret_cast<const float4*>(g + col);
        const float4 bv = *reinterpret_cast<const float4*>(bb + col);
        unsigned short pk[4];
        pk[0] = f2bf((v[i].x - mu) * r * gg.x + bv.x);
        pk[1] = f2bf((v[i].y - mu) * r * gg.y + bv.y);
        pk[2] = f2bf((v[i].z - mu) * r * gg.z + bv.z);
        pk[3] = f2bf((v[i].w - mu) * r * gg.w + bv.w);
        *reinterpret_cast<int2*>(orow + col) = *reinterpret_cast<const int2*>(pk);
    }
}

// ---------------------------------------------------------------------------
// GEMM 256x128, 8 waves (4M x 2N), single-buffer 2-barrier loop.
// Better staging ratio than 128x128: 48KB staged per 256 MFMAs.
// EPI: 2 = bias+gelu -> bf16 ; 3 = fused QKV scatter.
// ---------------------------------------------------------------------------
template <int EPI>
__global__ __launch_bounds__(512) void gemm256(
    const bf16* __restrict__ A, const bf16* __restrict__ Bt,
    const float* __restrict__ bias,
    void* __restrict__ outp, const int* __restrict__ mask,
    bf16* __restrict__ Qb, bf16* __restrict__ Kb, bf16* __restrict__ Vt,
    int M, int N, int K)
{
    __shared__ alignas(16) char smem[65536];
    char* As = smem;            // 256 rows x 128B
    char* Bs = smem + 32768;    // 128 rows x 128B
    const int tid = threadIdx.x;
    const int lane = tid & 63;
    const int wave = tid >> 6;            // 0..7
    const int wm = wave >> 1, wn = wave & 1;
    const int lr = lane & 15, lg = lane >> 4;
    const int bm = blockIdx.x, bn = blockIdx.y;

    f32x4 acc[4][4] = {};

    const size_t a_row0 = (size_t)bm * 256;
    const size_t b_row0 = (size_t)bn * 128;

    for (int kt = 0; kt < K; kt += 64) {
        #pragma unroll
        for (int i = 0; i < 4; ++i) {
            const int id = tid + i * 512;
            const int row = id >> 3, c = id & 7;
            const int cs = (c ^ (row & 7)) * 8;
            gload_lds16(A + (a_row0 + row) * K + kt + cs, As + id * 16);
        }
        #pragma unroll
        for (int i = 0; i < 2; ++i) {
            const int id = tid + i * 512;
            const int row = id >> 3, c = id & 7;
            const int cs = (c ^ (row & 7)) * 8;
            gload_lds16(Bt + (b_row0 + row) * K + kt + cs, Bs + id * 16);
        }
        __syncthreads();
        #pragma unroll
        for (int ks = 0; ks < 2; ++ks) {
            s16x8 af[4], bfr[4];
            #pragma unroll
            for (int mf = 0; mf < 4; ++mf) {
                const int row = wm * 64 + mf * 16 + lr;
                const int c = ks * 4 + lg;
                af[mf] = *reinterpret_cast<const s16x8*>(As + row * 128 + ((c ^ (row & 7)) * 16));
            }
            #pragma unroll
            for (int nf = 0; nf < 4; ++nf) {
                const int row = wn * 64 + nf * 16 + lr;
                const int c = ks * 4 + lg;
                bfr[nf] = *reinterpret_cast<const s16x8*>(Bs + row * 128 + ((c ^ (row & 7)) * 16));
            }
            #pragma unroll
            for (int mf = 0; mf < 4; ++mf)
                #pragma unroll
                for (int nf = 0; nf < 4; ++nf)
                    acc[mf][nf] = __builtin_amdgcn_mfma_f32_16x16x32_bf16(
                        af[mf], bfr[nf], acc[mf][nf], 0, 0, 0);
        }
        __syncthreads();
    }

    if (EPI == 3) {
        const int rq = bn / 6;                       // 0=q, 1=k, 2=v
        const int bb_ = bm >> 3;                     // batch (2048/256 = 8 tiles)
        if (rq == 2) {
            // V: acc -> per-wave LDS tile (swizzled) -> coalesced Vt stores.
            char* Ws = smem + wave * 8192;
            #pragma unroll
            for (int nf = 0; nf < 4; ++nf) {
                const int cl = nf * 16 + lr;
                const int gn = bn * 128 + wn * 64 + nf * 16 + lr;
                const float bs = bias[gn];
                #pragma unroll
                for (int mf = 0; mf < 4; ++mf) {
                    unsigned short pk[4];
                    #pragma unroll
                    for (int i = 0; i < 4; ++i) pk[i] = f2bf(acc[mf][nf][i] + bs);
                    const int slot = (2 * mf + (lg >> 1)) ^ (cl & 7);
                    *reinterpret_cast<long long*>(Ws + cl * 128 + slot * 16 + (lg & 1) * 8) =
                        *reinterpret_cast<const long long*>(pk);
                }
            }
            __syncthreads();
            const int nb = (bm * 256 + wm * 64) & 2047;
            const int cb = (bn - 12) * 128 + wn * 64;
            #pragma unroll
            for (int r = 0; r < 8; ++r) {
                const int cl = r * 8 + (lane >> 3);
                const int j = lane & 7;
                const int4 vv = *reinterpret_cast<const int4*>(
                    Ws + cl * 128 + ((j ^ (cl & 7)) * 16));
                const int c = cb + cl;
                const int hh = c >> 6, dd = c & 63;
                *reinterpret_cast<int4*>(
                    Vt + ((size_t)(bb_ * 12 + hh) * 64 + dd) * 2048 + nb + j * 8) = vv;
            }
        } else {
            const int cb = bn * 128 - rq * 768 + wn * 64;
            bf16* dst = (rq == 0) ? Qb : Kb;
            #pragma unroll
            for (int mf = 0; mf < 4; ++mf) {
                #pragma unroll
                for (int i = 0; i < 4; ++i) {
                    const int gm = bm * 256 + wm * 64 + mf * 16 + 4 * lg + i;
                    const int n = gm & 2047;
                    const float msc = (rq == 0) ? (mask[gm] ? QSCALE : 0.f) : 1.f;
                    #pragma unroll
                    for (int nf = 0; nf < 4; ++nf) {
                        const int c = cb + nf * 16 + lr;
                        const int h = c >> 6, d = c & 63;
                        const int gn = bn * 128 + wn * 64 + nf * 16 + lr;
                        const float v = (acc[mf][nf][i] + bias[gn]) * msc;
                        dst[((size_t)(bb_ * 12 + h) * 2048 + n) * 64 + d] =
                            __float2bfloat16(v);
                    }
                }
            }
        }
        return;
    }

    #pragma unroll
    for (int mf = 0; mf < 4; ++mf) {
        #pragma unroll
        for (int i = 0; i < 4; ++i) {
            const int gm = bm * 256 + wm * 64 + mf * 16 + 4 * lg + i;
            #pragma unroll
            for (int nf = 0; nf < 4; ++nf) {
                const int gn = bn * 128 + wn * 64 + nf * 16 + lr;
                float v = acc[mf][nf][i] + bias[gn];
                if (EPI == 2) {
                    // gelu(x) = x - x/(1+e^{2y}), y = 0.79788456(x+0.044715x^3)
                    const float x3 = v * v * v;
                    const float z = fmaf(x3, 0.044715f, v) * 2.3022080f;
                    const float e = __builtin_amdgcn_exp2f(z);
                    v = v - v * __builtin_amdgcn_rcpf(1.f + e);
                }
                reinterpret_cast<bf16*>(outp)[(size_t)gm * N + gn] = __float2bfloat16(v);
            }
        }
    }
}

// ---------------------------------------------------------------------------
// GEMM 64x128 (grid-balanced variant for proj / FC2, both bias+resid->fp32).
// ---------------------------------------------------------------------------
__global__ __launch_bounds__(256) void gemm64(
    const bf16* __restrict__ A, const bf16* __restrict__ Bt,
    const float* __restrict__ bias, const float* __restrict__ resid,
    float* __restrict__ outp, int M, int N, int K)
{
    __shared__ alignas(16) char smem[24576];
    char* As = smem;             // 64 rows x 128B
    char* Bs = smem + 8192;      // 128 rows x 128B
    const int tid = threadIdx.x;
    const int lane = tid & 63;
    const int wn = tid >> 6;     // wave 0..3 -> N strip
    const int lr = lane & 15, lg = lane >> 4;
    const int bm = blockIdx.x, bn = blockIdx.y;

    f32x4 acc[4][2] = {};

    const size_t a_row0 = (size_t)bm * 64;
    const size_t b_row0 = (size_t)bn * 128;

    for (int kt = 0; kt < K; kt += 64) {
        #pragma unroll
        for (int i = 0; i < 2; ++i) {
            const int id = tid + i * 256;
            const int row = id >> 3, c = id & 7;
            const int cs = (c ^ (row & 7)) * 8;
            gload_lds16(A + (a_row0 + row) * K + kt + cs, As + id * 16);
        }
        #pragma unroll
        for (int i = 0; i < 4; ++i) {
            const int id = tid + i * 256;
            const int row = id >> 3, c = id & 7;
            const int cs = (c ^ (row & 7)) * 8;
            gload_lds16(Bt + (b_row0 + row) * K + kt + cs, Bs + id * 16);
        }
        __syncthreads();
        #pragma unroll
        for (int ks = 0; ks < 2; ++ks) {
            s16x8 af[4], bfr[2];
            #pragma unroll
            for (int mf = 0; mf < 4; ++mf) {
                const int row = mf * 16 + lr;
                const int c = ks * 4 + lg;
                af[mf] = *reinterpret_cast<const s16x8*>(As + row * 128 + ((c ^ (row & 7)) * 16));
            }
            #pragma unroll
            for (int nf = 0; nf < 2; ++nf) {
                const int row = wn * 32 + nf * 16 + lr;
                const int c = ks * 4 + lg;
                bfr[nf] = *reinterpret_cast<const s16x8*>(Bs + row * 128 + ((c ^ (row & 7)) * 16));
            }
            #pragma unroll
            for (int mf = 0; mf < 4; ++mf)
                #pragma unroll
                for (int nf = 0; nf < 2; ++nf)
                    acc[mf][nf] = __builtin_amdgcn_mfma_f32_16x16x32_bf16(
                        af[mf], bfr[nf], acc[mf][nf], 0, 0, 0);
        }
        __syncthreads();
    }

    #pragma unroll
    for (int mf = 0; mf < 4; ++mf) {
        #pragma unroll
        for (int i = 0; i < 4; ++i) {
            const int gm = bm * 64 + mf * 16 + 4 * lg + i;
            #pragma unroll
            for (int nf = 0; nf < 2; ++nf) {
                const int gn = bn * 128 + wn * 32 + nf * 16 + lr;
                outp[(size_t)gm * N + gn] =
                    acc[mf][nf][i] + bias[gn] + resid[(size_t)gm * N + gn];
            }
        }
    }
}

// ---------------------------------------------------------------------------
// Flash attention (R10/R12 structure): static-max softmax (p = exp2(st)),
// ones-MFMA row sum, dbuf staging, XCD remap, conflict-free LDS swizzle.
// ---------------------------------------------------------------------------
__global__ __launch_bounds__(256, 3) void attn_kernel(
    const bf16* __restrict__ Qb, const bf16* __restrict__ Kb,
    const bf16* __restrict__ Vt, bf16* __restrict__ out)
{
    __shared__ alignas(16) char Ks[2][64 * 128];
    __shared__ alignas(16) char Vs[2][64 * 128];

    const int lin = blockIdx.x;            // 768 blocks
    const int xcd = lin & 7, slot = lin >> 3;
    const int pair = xcd * 6 + (slot >> 4);   // 0..47
    const int qb = slot & 15;
    const int b = pair / 12, h = pair % 12;

    const int tid = threadIdx.x, lane = tid & 63, wave = tid >> 6;
    const int lq = lane & 31;
    const int hi = lane >> 5;
    const size_t bh = (size_t)(b * 12 + h);
    const bf16* Kh = Kb + bh * 2048 * 64;
    const bf16* Vh = Vt + bh * 64 * 2048;
    const int q0w = qb * 128 + wave * 32;

    s16x8 qf[4];
    {
        const bf16* qp = Qb + (bh * 2048 + q0w + lq) * 64 + 8 * hi;
        #pragma unroll
        for (int ks = 0; ks < 4; ++ks)
            qf[ks] = *reinterpret_cast<const s16x8*>(qp + 16 * ks);
    }
    const int4 onesw = {0x3F803F80, 0x3F803F80, 0x3F803F80, 0x3F803F80};
    const s16x8 onesf = __builtin_bit_cast(s16x8, onesw);

    int sKoff0, sKoff1, dst0, dst1;
    size_t sVoff0, sVoff1;
    {
        const int id0 = tid;
        const int R0 = id0 >> 4;
        const int u0 = (id0 & 15) ^ (R0 & 15);
        const int rt0 = 2 * R0 + (u0 >> 3), s80 = (u0 & 7) * 8;
        sKoff0 = rt0 * 64 + s80;
        sVoff0 = (size_t)rt0 * 2048 + s80;
        dst0 = id0 * 16;
        const int id1 = tid + 256;
        const int R1 = id1 >> 4;
        const int u1 = (id1 & 15) ^ (R1 & 15);
        const int rt1 = 2 * R1 + (u1 >> 3), s81 = (u1 & 7) * 8;
        sKoff1 = rt1 * 64 + s81;
        sVoff1 = (size_t)rt1 * 2048 + s81;
        dst1 = id1 * 16;
    }

    const int rh = lq >> 1;
    const int m7 = rh & 7;
    const int rbase = rh * 256 + (((((lq & 1) << 3) ^ (rh & 8))) << 4);

    f32x16 o0 = {}, o1 = {};   // O^T accumulators: d 0..31 / 32..63
    f32x16 os = {};            // row-sum accumulator (all rows equal)

    #define STAGE(buf, kb)                                                    \
        do {                                                                  \
            gload_lds16(Kh + (kb) * 4096 + sKoff0, Ks[buf] + dst0);           \
            gload_lds16(Vh + (kb) * 64 + sVoff0, Vs[buf] + dst0);             \
            gload_lds16(Kh + (kb) * 4096 + sKoff1, Ks[buf] + dst1);           \
            gload_lds16(Vh + (kb) * 64 + sVoff1, Vs[buf] + dst1);             \
        } while (0)

    STAGE(0, 0);
    __syncthreads();
    int cur = 0;

    for (int kb = 0; kb < 32; ++kb) {
        if (kb < 31) STAGE(cur ^ 1, kb + 1);
        const char* Kc = Ks[cur] + rbase;
        const char* Vc = Vs[cur] + rbase;

        // ---- S^T (log2 domain) for both 32-key subtiles: 8 MFMAs ----
        f32x16 st0 = {}, st1 = {};
        __builtin_amdgcn_s_setprio(1);
        #pragma unroll
        for (int ks = 0; ks < 4; ++ks) {
            const int so = (((2 * ks + hi) ^ m7) << 4);
            const s16x8 kf0 = *reinterpret_cast<const s16x8*>(Kc + so);
            st0 = __builtin_amdgcn_mfma_f32_32x32x16_bf16(kf0, qf[ks], st0, 0, 0, 0);
            const s16x8 kf1 = *reinterpret_cast<const s16x8*>(Kc + 4096 + so);
            st1 = __builtin_amdgcn_mfma_f32_32x32x16_bf16(kf1, qf[ks], st1, 0, 0, 0);
        }
        __builtin_amdgcn_s_setprio(0);

        // ---- static-max softmax: p = exp2(st) ----
        float p0[16], p1[16];
        #pragma unroll
        for (int r = 0; r < 16; ++r) {
            p0[r] = __builtin_amdgcn_exp2f(st0[r]);
            p1[r] = __builtin_amdgcn_exp2f(st1[r]);
        }

        // ---- P^T B-frags (4 x 16 keys) ----
        const s16x8 pf00 = build_pfrag(p0[0], p0[1], p0[2], p0[3], p0[4], p0[5], p0[6], p0[7]);
        const s16x8 pf01 = build_pfrag(p0[8], p0[9], p0[10], p0[11], p0[12], p0[13], p0[14], p0[15]);
        const s16x8 pf10 = build_pfrag(p1[0], p1[1], p1[2], p1[3], p1[4], p1[5], p1[6], p1[7]);
        const s16x8 pf11 = build_pfrag(p1[8], p1[9], p1[10], p1[11], p1[12], p1[13], p1[14], p1[15]);

        // ---- O^T += V^T * P^T ; l += 1 . P (matrix pipe) ----
        __builtin_amdgcn_s_setprio(1);
        #pragma unroll
        for (int kf4 = 0; kf4 < 4; ++kf4) {
            const s16x8 pf = (kf4 == 0) ? pf00 : (kf4 == 1) ? pf01
                           : (kf4 == 2) ? pf10 : pf11;
            const int so = (((2 * kf4 + hi) ^ m7) << 4);
            const s16x8 vf0 = *reinterpret_cast<const s16x8*>(Vc + so);
            o0 = __builtin_amdgcn_mfma_f32_32x32x16_bf16(vf0, pf, o0, 0, 0, 0);
            const s16x8 vf1 = *reinterpret_cast<const s16x8*>(Vc + 4096 + so);
            o1 = __builtin_amdgcn_mfma_f32_32x32x16_bf16(vf1, pf, o1, 0, 0, 0);
            os = __builtin_amdgcn_mfma_f32_32x32x16_bf16(onesf, pf, os, 0, 0, 0);
        }
        __builtin_amdgcn_s_setprio(0);

        __syncthreads();
        cur ^= 1;
    }
    #undef STAGE

    const float rl = 1.0f / os[0];   // l for q = lane&31 (all rows equal)
    bf16* orow = out + (size_t)(b * 2048 + q0w + lq) * 768 + h * 64;
    #pragma unroll
    for (int g = 0; g < 4; ++g) {
        unsigned short pk0[4], pk1[4];
        #pragma unroll
        for (int i = 0; i < 4; ++i) {
            pk0[i] = f2bf(o0[4 * g + i] * rl);
            pk1[i] = f2bf(o1[4 * g + i] * rl);
        }
        const int d0 = 8 * g + 4 * hi;
        *reinterpret_cast<int2*>(orow + d0) = *reinterpret_cast<const int2*>(pk0);
        *reinterpret_cast<int2*>(orow + 32 + d0) = *reinterpret_cast<const int2*>(pk1);
    }
}

// ---------------------------------------------------------------------------
// Launch
// ---------------------------------------------------------------------------
extern "C" void kernel_launch(void* const* d_in, const int* in_sizes, int n_in,
                              void* d_out, int out_size, void* d_ws, size_t ws_size,
                              hipStream_t stream)
{
    (void)in_sizes; (void)n_in; (void)out_size; (void)ws_size;
    const float* x      = (const float*)d_in[0];
    const int*   mask   = (const int*)d_in[1];
    const float* ln1_g  = (const float*)d_in[2];
    const float* ln1_b  = (const float*)d_in[3];
    const float* qkv_w  = (const float*)d_in[4];
    const float* qkv_b  = (const float*)d_in[5];
    const float* proj_w = (const float*)d_in[6];
    const float* proj_b = (const float*)d_in[7];
    const float* ln2_g  = (const float*)d_in[8];
    const float* ln2_b  = (const float*)d_in[9];
    const float* fc1_w  = (const float*)d_in[10];
    const float* fc1_b  = (const float*)d_in[11];
    const float* fc2_w  = (const float*)d_in[12];
    const float* fc2_b  = (const float*)d_in[13];
    float* out = (float*)d_out;
    char* ws = (char*)d_ws;

    bf16*  Wt_qkv  = (bf16*)(ws + 0);          // [2304][768]
    bf16*  Wt_proj = (bf16*)(ws + 3538944);    // [768][768]
    bf16*  Wt_fc1  = (bf16*)(ws + 4718592);    // [3072][768]
    bf16*  Wt_fc2  = (bf16*)(ws + 9437184);    // [768][3072]
    bf16*  hbuf    = (bf16*)(ws + 14155776);   // [8192][768]
    bf16*  attnout = (bf16*)(ws + 64487424);   // [8192][768]
    float* x1      = (float*)(ws + 77070336);  // [8192][768]
    bf16*  h2      = (bf16*)(ws + 102236160);  // [8192][768]
    bf16*  a1      = (bf16*)(ws + 114819072);  // [8192][3072] (FC1 out)
    bf16*  Qb      = (bf16*)(ws + 114819072);  // overlay: [4][12][2048][64]
    bf16*  Kb      = (bf16*)(ws + 127401984);
    bf16*  Vt      = (bf16*)(ws + 139984896);

    transpose_all<<<6912, dim3(32, 8), 0, stream>>>(
        qkv_w, proj_w, fc1_w, fc2_w, Wt_qkv, Wt_proj, Wt_fc1, Wt_fc2);

    ln_kernel<<<2048, 256, 0, stream>>>(x, ln1_g, ln1_b, hbuf);
    gemm256<3><<<dim3(32, 18), 512, 0, stream>>>(hbuf, Wt_qkv, qkv_b, nullptr,
                                                 mask, Qb, Kb, Vt, 8192, 2304, 768);
    attn_kernel<<<768, 256, 0, stream>>>(Qb, Kb, Vt, attnout);
    gemm64<<<dim3(128, 6), 256, 0, stream>>>(attnout, Wt_proj, proj_b, x, x1,
                                             8192, 768, 768);
    ln_kernel<<<2048, 256, 0, stream>>>(x1, ln2_g, ln2_b, h2);
    gemm256<2><<<dim3(32, 24), 512, 0, stream>>>(h2, Wt_fc1, fc1_b, a1,
                                                 nullptr, nullptr, nullptr, nullptr, 8192, 3072, 768);
    gemm64<<<dim3(128, 6), 256, 0, stream>>>(a1, Wt_fc2, fc2_b, x1, out,
                                             8192, 768, 3072);
}

// Round 14
// 238.009 us; speedup vs baseline: 1.0635x; 1.0144x over previous
//
#include <hip/hip_runtime.h>
#include <hip/hip_bf16.h>
#include <math.h>

using bf16 = __hip_bfloat16;
typedef short s16x8 __attribute__((ext_vector_type(8)));
typedef float f32x4 __attribute__((ext_vector_type(4)));
typedef float f32x16 __attribute__((ext_vector_type(16)));

#define LOG2E 1.4426950408889634f
// Q pre-scale: D^-0.5 * log2(e) so QK^T scores land directly in log2 domain.
#define QSCALE 0.18033688f

__device__ inline unsigned short f2bf(float f) {
    bf16 h = __float2bfloat16(f);
    return __builtin_bit_cast(unsigned short, h);
}

__device__ inline float bf2f(unsigned short u) {
    unsigned v = (unsigned)u << 16;
    return __builtin_bit_cast(float, v);
}

// async global->LDS, 16B per lane. Dest must be wave-linear (base + lane*16).
__device__ inline void gload_lds16(const void* g, void* l) {
    __builtin_amdgcn_global_load_lds(
        (const __attribute__((address_space(1))) void*)g,
        (__attribute__((address_space(3))) void*)l, 16, 0, 0);
}

__device__ inline unsigned cvtpk(float lo, float hi) {
    unsigned r;
    asm("v_cvt_pk_bf16_f32 %0, %1, %2" : "=v"(r) : "v"(lo), "v"(hi));
    return r;
}

// Build PV B-operand fragment from 8 in-lane P values (verified mapping).
__device__ inline s16x8 build_pfrag(float p0, float p1, float p2, float p3,
                                    float p4, float p5, float p6, float p7) {
    unsigned w01 = cvtpk(p0, p1);
    unsigned w23 = cvtpk(p2, p3);
    unsigned w45 = cvtpk(p4, p5);
    unsigned w67 = cvtpk(p6, p7);
    asm volatile("v_permlane32_swap_b32 %0, %1" : "+v"(w01), "+v"(w45));
    asm volatile("v_permlane32_swap_b32 %0, %1" : "+v"(w23), "+v"(w67));
    int4 t = {(int)w01, (int)w23, (int)w45, (int)w67};
    return __builtin_bit_cast(s16x8, t);
}

// ---------------------------------------------------------------------------
// Merged weight prep: all four W -> W^T bf16 in ONE launch.
// ---------------------------------------------------------------------------
__global__ __launch_bounds__(256) void transpose_all(
    const float* __restrict__ qkv_w, const float* __restrict__ proj_w,
    const float* __restrict__ fc1_w, const float* __restrict__ fc2_w,
    bf16* __restrict__ Wqkv, bf16* __restrict__ Wproj,
    bf16* __restrict__ Wfc1, bf16* __restrict__ Wfc2)
{
    int t = blockIdx.x;
    const float* in;
    bf16* out;
    int K, N, xt;
    if (t < 1728)      { in = qkv_w;  out = Wqkv;  K = 768;  N = 2304; xt = 72; }
    else if (t < 2304) { in = proj_w; out = Wproj; K = 768;  N = 768;  xt = 24; t -= 1728; }
    else if (t < 4608) { in = fc1_w;  out = Wfc1;  K = 768;  N = 3072; xt = 96; t -= 2304; }
    else               { in = fc2_w;  out = Wfc2;  K = 3072; N = 768;  xt = 24; t -= 4608; }
    const int bx = (t % xt) * 32;  // n
    const int by = (t / xt) * 32;  // k

    __shared__ float tile[32][33];
    const int tx = threadIdx.x, ty = threadIdx.y;  // 32 x 8
    #pragma unroll
    for (int i = 0; i < 32; i += 8)
        tile[ty + i][tx] = in[(size_t)(by + ty + i) * N + bx + tx];
    __syncthreads();
    #pragma unroll
    for (int i = 0; i < 32; i += 8)
        out[(size_t)(bx + ty + i) * K + by + tx] = __float2bfloat16(tile[tx][ty + i]);
}

// ---------------------------------------------------------------------------
// LayerNorm over C=768, fp32 in -> bf16 out. ONE WAVE PER ROW (4 rows/block).
// ---------------------------------------------------------------------------
__global__ __launch_bounds__(256) void ln_kernel(
    const float* __restrict__ x, const float* __restrict__ g,
    const float* __restrict__ bb, bf16* __restrict__ out)
{
    const int wave = threadIdx.x >> 6, lane = threadIdx.x & 63;
    const int row = blockIdx.x * 4 + wave;
    const float* xr = x + (size_t)row * 768;
    float4 v[3];
    float s = 0.f, s2 = 0.f;
    #pragma unroll
    for (int i = 0; i < 3; ++i) {
        v[i] = *reinterpret_cast<const float4*>(xr + (lane + 64 * i) * 4);
        s += (v[i].x + v[i].y) + (v[i].z + v[i].w);
        s2 += (v[i].x * v[i].x + v[i].y * v[i].y) + (v[i].z * v[i].z + v[i].w * v[i].w);
    }
    #pragma unroll
    for (int off = 1; off < 64; off <<= 1) {
        s += __shfl_xor(s, off);
        s2 += __shfl_xor(s2, off);
    }
    const float mu = s * (1.f / 768.f);
    const float var = s2 * (1.f / 768.f) - mu * mu;
    const float r = rsqrtf(var + 1e-6f);
    bf16* orow = out + (size_t)row * 768;
    #pragma unroll
    for (int i = 0; i < 3; ++i) {
        const int col = (lane + 64 * i) * 4;
        const float4 gg = *reinterpret_cast<const float4*>(g + col);
        const float4 bv = *reinterpret_cast<const float4*>(bb + col);
        unsigned short pk[4];
        pk[0] = f2bf((v[i].x - mu) * r * gg.x + bv.x);
        pk[1] = f2bf((v[i].y - mu) * r * gg.y + bv.y);
        pk[2] = f2bf((v[i].z - mu) * r * gg.z + bv.z);
        pk[3] = f2bf((v[i].w - mu) * r * gg.w + bv.w);
        *reinterpret_cast<int2*>(orow + col) = *reinterpret_cast<const int2*>(pk);
    }
}

// ---------------------------------------------------------------------------
// LayerNorm, bf16 input variant (for x1). 12 bf16/lane: one 16B + one 8B load.
// ---------------------------------------------------------------------------
__global__ __launch_bounds__(256) void ln_bf16_kernel(
    const bf16* __restrict__ x, const float* __restrict__ g,
    const float* __restrict__ bb, bf16* __restrict__ out)
{
    const int wave = threadIdx.x >> 6, lane = threadIdx.x & 63;
    const int row = blockIdx.x * 4 + wave;
    const bf16* xr = x + (size_t)row * 768;
    unsigned short e[12];
    *reinterpret_cast<int4*>(e) = *reinterpret_cast<const int4*>(xr + lane * 8);
    *reinterpret_cast<int2*>(e + 8) = *reinterpret_cast<const int2*>(xr + 512 + lane * 4);
    float f[12];
    float s = 0.f, s2 = 0.f;
    #pragma unroll
    for (int i = 0; i < 12; ++i) {
        f[i] = bf2f(e[i]);
        s += f[i];
        s2 += f[i] * f[i];
    }
    #pragma unroll
    for (int off = 1; off < 64; off <<= 1) {
        s += __shfl_xor(s, off);
        s2 += __shfl_xor(s2, off);
    }
    const float mu = s * (1.f / 768.f);
    const float var = s2 * (1.f / 768.f) - mu * mu;
    const float r = rsqrtf(var + 1e-6f);
    bf16* orow = out + (size_t)row * 768;
    unsigned short pk[12];
    #pragma unroll
    for (int i = 0; i < 8; ++i) {
        const int col = lane * 8 + i;
        pk[i] = f2bf((f[i] - mu) * r * g[col] + bb[col]);
    }
    #pragma unroll
    for (int i = 0; i < 4; ++i) {
        const int col = 512 + lane * 4 + i;
        pk[8 + i] = f2bf((f[8 + i] - mu) * r * g[col] + bb[col]);
    }
    *reinterpret_cast<int4*>(orow + lane * 8) = *reinterpret_cast<const int4*>(pk);
    *reinterpret_cast<int2*>(orow + 512 + lane * 4) = *reinterpret_cast<const int2*>(pk + 8);
}

// ---------------------------------------------------------------------------
// GEMM 256x128, 8 waves (4M x 2N), single-buffer 2-barrier loop.
// EPI: 2 = bias+gelu -> bf16 ; 3 = fused QKV scatter.
// ---------------------------------------------------------------------------
template <int EPI>
__global__ __launch_bounds__(512) void gemm256(
    const bf16* __restrict__ A, const bf16* __restrict__ Bt,
    const float* __restrict__ bias,
    void* __restrict__ outp, const int* __restrict__ mask,
    bf16* __restrict__ Qb, bf16* __restrict__ Kb, bf16* __restrict__ Vt,
    int M, int N, int K)
{
    __shared__ alignas(16) char smem[65536];
    char* As = smem;            // 256 rows x 128B
    char* Bs = smem + 32768;    // 128 rows x 128B
    const int tid = threadIdx.x;
    const int lane = tid & 63;
    const int wave = tid >> 6;            // 0..7
    const int wm = wave >> 1, wn = wave & 1;
    const int lr = lane & 15, lg = lane >> 4;
    const int bm = blockIdx.x, bn = blockIdx.y;

    f32x4 acc[4][4] = {};

    const size_t a_row0 = (size_t)bm * 256;
    const size_t b_row0 = (size_t)bn * 128;

    for (int kt = 0; kt < K; kt += 64) {
        #pragma unroll
        for (int i = 0; i < 4; ++i) {
            const int id = tid + i * 512;
            const int row = id >> 3, c = id & 7;
            const int cs = (c ^ (row & 7)) * 8;
            gload_lds16(A + (a_row0 + row) * K + kt + cs, As + id * 16);
        }
        #pragma unroll
        for (int i = 0; i < 2; ++i) {
            const int id = tid + i * 512;
            const int row = id >> 3, c = id & 7;
            const int cs = (c ^ (row & 7)) * 8;
            gload_lds16(Bt + (b_row0 + row) * K + kt + cs, Bs + id * 16);
        }
        __syncthreads();
        #pragma unroll
        for (int ks = 0; ks < 2; ++ks) {
            s16x8 af[4], bfr[4];
            #pragma unroll
            for (int mf = 0; mf < 4; ++mf) {
                const int row = wm * 64 + mf * 16 + lr;
                const int c = ks * 4 + lg;
                af[mf] = *reinterpret_cast<const s16x8*>(As + row * 128 + ((c ^ (row & 7)) * 16));
            }
            #pragma unroll
            for (int nf = 0; nf < 4; ++nf) {
                const int row = wn * 64 + nf * 16 + lr;
                const int c = ks * 4 + lg;
                bfr[nf] = *reinterpret_cast<const s16x8*>(Bs + row * 128 + ((c ^ (row & 7)) * 16));
            }
            #pragma unroll
            for (int mf = 0; mf < 4; ++mf)
                #pragma unroll
                for (int nf = 0; nf < 4; ++nf)
                    acc[mf][nf] = __builtin_amdgcn_mfma_f32_16x16x32_bf16(
                        af[mf], bfr[nf], acc[mf][nf], 0, 0, 0);
        }
        __syncthreads();
    }

    if (EPI == 3) {
        const int rq = bn / 6;                       // 0=q, 1=k, 2=v
        const int bb_ = bm >> 3;                     // batch (2048/256 = 8 tiles)
        if (rq == 2) {
            char* Ws = smem + wave * 8192;
            #pragma unroll
            for (int nf = 0; nf < 4; ++nf) {
                const int cl = nf * 16 + lr;
                const int gn = bn * 128 + wn * 64 + nf * 16 + lr;
                const float bs = bias[gn];
                #pragma unroll
                for (int mf = 0; mf < 4; ++mf) {
                    unsigned short pk[4];
                    #pragma unroll
                    for (int i = 0; i < 4; ++i) pk[i] = f2bf(acc[mf][nf][i] + bs);
                    const int slot = (2 * mf + (lg >> 1)) ^ (cl & 7);
                    *reinterpret_cast<long long*>(Ws + cl * 128 + slot * 16 + (lg & 1) * 8) =
                        *reinterpret_cast<const long long*>(pk);
                }
            }
            __syncthreads();
            const int nb = (bm * 256 + wm * 64) & 2047;
            const int cb = (bn - 12) * 128 + wn * 64;
            #pragma unroll
            for (int r = 0; r < 8; ++r) {
                const int cl = r * 8 + (lane >> 3);
                const int j = lane & 7;
                const int4 vv = *reinterpret_cast<const int4*>(
                    Ws + cl * 128 + ((j ^ (cl & 7)) * 16));
                const int c = cb + cl;
                const int hh = c >> 6, dd = c & 63;
                *reinterpret_cast<int4*>(
                    Vt + ((size_t)(bb_ * 12 + hh) * 64 + dd) * 2048 + nb + j * 8) = vv;
            }
        } else {
            const int cb = bn * 128 - rq * 768 + wn * 64;
            bf16* dst = (rq == 0) ? Qb : Kb;
            #pragma unroll
            for (int mf = 0; mf < 4; ++mf) {
                #pragma unroll
                for (int i = 0; i < 4; ++i) {
                    const int gm = bm * 256 + wm * 64 + mf * 16 + 4 * lg + i;
                    const int n = gm & 2047;
                    const float msc = (rq == 0) ? (mask[gm] ? QSCALE : 0.f) : 1.f;
                    #pragma unroll
                    for (int nf = 0; nf < 4; ++nf) {
                        const int c = cb + nf * 16 + lr;
                        const int h = c >> 6, d = c & 63;
                        const int gn = bn * 128 + wn * 64 + nf * 16 + lr;
                        const float v = (acc[mf][nf][i] + bias[gn]) * msc;
                        dst[((size_t)(bb_ * 12 + h) * 2048 + n) * 64 + d] =
                            __float2bfloat16(v);
                    }
                }
            }
        }
        return;
    }

    #pragma unroll
    for (int mf = 0; mf < 4; ++mf) {
        #pragma unroll
        for (int i = 0; i < 4; ++i) {
            const int gm = bm * 256 + wm * 64 + mf * 16 + 4 * lg + i;
            #pragma unroll
            for (int nf = 0; nf < 4; ++nf) {
                const int gn = bn * 128 + wn * 64 + nf * 16 + lr;
                float v = acc[mf][nf][i] + bias[gn];
                if (EPI == 2) {
                    // gelu(x) = x - x/(1+e^{2y}), y = 0.79788456(x+0.044715x^3)
                    const float x3 = v * v * v;
                    const float z = fmaf(x3, 0.044715f, v) * 2.3022080f;
                    const float e = __builtin_amdgcn_exp2f(z);
                    v = v - v * __builtin_amdgcn_rcpf(1.f + e);
                }
                reinterpret_cast<bf16*>(outp)[(size_t)gm * N + gn] = __float2bfloat16(v);
            }
        }
    }
}

// ---------------------------------------------------------------------------
// GEMM 64x128 (grid-balanced, proj / FC2).
// EPI64: 0 = proj: resid fp32, out bf16 ; 1 = fc2: resid bf16, out fp32.
// ---------------------------------------------------------------------------
template <int EPI64>
__global__ __launch_bounds__(256) void gemm64(
    const bf16* __restrict__ A, const bf16* __restrict__ Bt,
    const float* __restrict__ bias, const void* __restrict__ resid,
    void* __restrict__ outp, int M, int N, int K)
{
    __shared__ alignas(16) char smem[24576];
    char* As = smem;             // 64 rows x 128B
    char* Bs = smem + 8192;      // 128 rows x 128B
    const int tid = threadIdx.x;
    const int lane = tid & 63;
    const int wn = tid >> 6;     // wave 0..3 -> N strip
    const int lr = lane & 15, lg = lane >> 4;
    const int bm = blockIdx.x, bn = blockIdx.y;

    f32x4 acc[4][2] = {};

    const size_t a_row0 = (size_t)bm * 64;
    const size_t b_row0 = (size_t)bn * 128;

    for (int kt = 0; kt < K; kt += 64) {
        #pragma unroll
        for (int i = 0; i < 2; ++i) {
            const int id = tid + i * 256;
            const int row = id >> 3, c = id & 7;
            const int cs = (c ^ (row & 7)) * 8;
            gload_lds16(A + (a_row0 + row) * K + kt + cs, As + id * 16);
        }
        #pragma unroll
        for (int i = 0; i < 4; ++i) {
            const int id = tid + i * 256;
            const int row = id >> 3, c = id & 7;
            const int cs = (c ^ (row & 7)) * 8;
            gload_lds16(Bt + (b_row0 + row) * K + kt + cs, Bs + id * 16);
        }
        __syncthreads();
        #pragma unroll
        for (int ks = 0; ks < 2; ++ks) {
            s16x8 af[4], bfr[2];
            #pragma unroll
            for (int mf = 0; mf < 4; ++mf) {
                const int row = mf * 16 + lr;
                const int c = ks * 4 + lg;
                af[mf] = *reinterpret_cast<const s16x8*>(As + row * 128 + ((c ^ (row & 7)) * 16));
            }
            #pragma unroll
            for (int nf = 0; nf < 2; ++nf) {
                const int row = wn * 32 + nf * 16 + lr;
                const int c = ks * 4 + lg;
                bfr[nf] = *reinterpret_cast<const s16x8*>(Bs + row * 128 + ((c ^ (row & 7)) * 16));
            }
            #pragma unroll
            for (int mf = 0; mf < 4; ++mf)
                #pragma unroll
                for (int nf = 0; nf < 2; ++nf)
                    acc[mf][nf] = __builtin_amdgcn_mfma_f32_16x16x32_bf16(
                        af[mf], bfr[nf], acc[mf][nf], 0, 0, 0);
        }
        __syncthreads();
    }

    #pragma unroll
    for (int mf = 0; mf < 4; ++mf) {
        #pragma unroll
        for (int i = 0; i < 4; ++i) {
            const int gm = bm * 64 + mf * 16 + 4 * lg + i;
            #pragma unroll
            for (int nf = 0; nf < 2; ++nf) {
                const int gn = bn * 128 + wn * 32 + nf * 16 + lr;
                const size_t idx = (size_t)gm * N + gn;
                float rv;
                if (EPI64 == 0) rv = reinterpret_cast<const float*>(resid)[idx];
                else            rv = __bfloat162float(reinterpret_cast<const bf16*>(resid)[idx]);
                const float v = acc[mf][nf][i] + bias[gn] + rv;
                if (EPI64 == 0)
                    reinterpret_cast<bf16*>(outp)[idx] = __float2bfloat16(v);
                else
                    reinterpret_cast<float*>(outp)[idx] = v;
            }
        }
    }
}

// ---------------------------------------------------------------------------
// Flash attention: static-max softmax (p = exp2(st)), ones-MFMA row sum,
// dbuf staging, XCD remap, conflict-free LDS swizzle.
// ---------------------------------------------------------------------------
__global__ __launch_bounds__(256, 3) void attn_kernel(
    const bf16* __restrict__ Qb, const bf16* __restrict__ Kb,
    const bf16* __restrict__ Vt, bf16* __restrict__ out)
{
    __shared__ alignas(16) char Ks[2][64 * 128];
    __shared__ alignas(16) char Vs[2][64 * 128];

    const int lin = blockIdx.x;            // 768 blocks
    const int xcd = lin & 7, slot = lin >> 3;
    const int pair = xcd * 6 + (slot >> 4);   // 0..47
    const int qb = slot & 15;
    const int b = pair / 12, h = pair % 12;

    const int tid = threadIdx.x, lane = tid & 63, wave = tid >> 6;
    const int lq = lane & 31;
    const int hi = lane >> 5;
    const size_t bh = (size_t)(b * 12 + h);
    const bf16* Kh = Kb + bh * 2048 * 64;
    const bf16* Vh = Vt + bh * 64 * 2048;
    const int q0w = qb * 128 + wave * 32;

    s16x8 qf[4];
    {
        const bf16* qp = Qb + (bh * 2048 + q0w + lq) * 64 + 8 * hi;
        #pragma unroll
        for (int ks = 0; ks < 4; ++ks)
            qf[ks] = *reinterpret_cast<const s16x8*>(qp + 16 * ks);
    }
    const int4 onesw = {0x3F803F80, 0x3F803F80, 0x3F803F80, 0x3F803F80};
    const s16x8 onesf = __builtin_bit_cast(s16x8, onesw);

    int sKoff0, sKoff1, dst0, dst1;
    size_t sVoff0, sVoff1;
    {
        const int id0 = tid;
        const int R0 = id0 >> 4;
        const int u0 = (id0 & 15) ^ (R0 & 15);
        const int rt0 = 2 * R0 + (u0 >> 3), s80 = (u0 & 7) * 8;
        sKoff0 = rt0 * 64 + s80;
        sVoff0 = (size_t)rt0 * 2048 + s80;
        dst0 = id0 * 16;
        const int id1 = tid + 256;
        const int R1 = id1 >> 4;
        const int u1 = (id1 & 15) ^ (R1 & 15);
        const int rt1 = 2 * R1 + (u1 >> 3), s81 = (u1 & 7) * 8;
        sKoff1 = rt1 * 64 + s81;
        sVoff1 = (size_t)rt1 * 2048 + s81;
        dst1 = id1 * 16;
    }

    const int rh = lq >> 1;
    const int m7 = rh & 7;
    const int rbase = rh * 256 + (((((lq & 1) << 3) ^ (rh & 8))) << 4);

    f32x16 o0 = {}, o1 = {};   // O^T accumulators: d 0..31 / 32..63
    f32x16 os = {};            // row-sum accumulator (all rows equal)

    #define STAGE(buf, kb)                                                    \
        do {                                                                  \
            gload_lds16(Kh + (kb) * 4096 + sKoff0, Ks[buf] + dst0);           \
            gload_lds16(Vh + (kb) * 64 + sVoff0, Vs[buf] + dst0);             \
            gload_lds16(Kh + (kb) * 4096 + sKoff1, Ks[buf] + dst1);           \
            gload_lds16(Vh + (kb) * 64 + sVoff1, Vs[buf] + dst1);             \
        } while (0)

    STAGE(0, 0);
    __syncthreads();
    int cur = 0;

    for (int kb = 0; kb < 32; ++kb) {
        if (kb < 31) STAGE(cur ^ 1, kb + 1);
        const char* Kc = Ks[cur] + rbase;
        const char* Vc = Vs[cur] + rbase;

        // ---- S^T (log2 domain) for both 32-key subtiles: 8 MFMAs ----
        f32x16 st0 = {}, st1 = {};
        __builtin_amdgcn_s_setprio(1);
        #pragma unroll
        for (int ks = 0; ks < 4; ++ks) {
            const int so = (((2 * ks + hi) ^ m7) << 4);
            const s16x8 kf0 = *reinterpret_cast<const s16x8*>(Kc + so);
            st0 = __builtin_amdgcn_mfma_f32_32x32x16_bf16(kf0, qf[ks], st0, 0, 0, 0);
            const s16x8 kf1 = *reinterpret_cast<const s16x8*>(Kc + 4096 + so);
            st1 = __builtin_amdgcn_mfma_f32_32x32x16_bf16(kf1, qf[ks], st1, 0, 0, 0);
        }
        __builtin_amdgcn_s_setprio(0);

        // ---- static-max softmax: p = exp2(st) ----
        float p0[16], p1[16];
        #pragma unroll
        for (int r = 0; r < 16; ++r) {
            p0[r] = __builtin_amdgcn_exp2f(st0[r]);
            p1[r] = __builtin_amdgcn_exp2f(st1[r]);
        }

        // ---- P^T B-frags (4 x 16 keys) ----
        const s16x8 pf00 = build_pfrag(p0[0], p0[1], p0[2], p0[3], p0[4], p0[5], p0[6], p0[7]);
        const s16x8 pf01 = build_pfrag(p0[8], p0[9], p0[10], p0[11], p0[12], p0[13], p0[14], p0[15]);
        const s16x8 pf10 = build_pfrag(p1[0], p1[1], p1[2], p1[3], p1[4], p1[5], p1[6], p1[7]);
        const s16x8 pf11 = build_pfrag(p1[8], p1[9], p1[10], p1[11], p1[12], p1[13], p1[14], p1[15]);

        // ---- O^T += V^T * P^T ; l += 1 . P (matrix pipe) ----
        __builtin_amdgcn_s_setprio(1);
        #pragma unroll
        for (int kf4 = 0; kf4 < 4; ++kf4) {
            const s16x8 pf = (kf4 == 0) ? pf00 : (kf4 == 1) ? pf01
                           : (kf4 == 2) ? pf10 : pf11;
            const int so = (((2 * kf4 + hi) ^ m7) << 4);
            const s16x8 vf0 = *reinterpret_cast<const s16x8*>(Vc + so);
            o0 = __builtin_amdgcn_mfma_f32_32x32x16_bf16(vf0, pf, o0, 0, 0, 0);
            const s16x8 vf1 = *reinterpret_cast<const s16x8*>(Vc + 4096 + so);
            o1 = __builtin_amdgcn_mfma_f32_32x32x16_bf16(vf1, pf, o1, 0, 0, 0);
            os = __builtin_amdgcn_mfma_f32_32x32x16_bf16(onesf, pf, os, 0, 0, 0);
        }
        __builtin_amdgcn_s_setprio(0);

        __syncthreads();
        cur ^= 1;
    }
    #undef STAGE

    const float rl = 1.0f / os[0];   // l for q = lane&31 (all rows equal)
    bf16* orow = out + (size_t)(b * 2048 + q0w + lq) * 768 + h * 64;
    #pragma unroll
    for (int g = 0; g < 4; ++g) {
        unsigned short pk0[4], pk1[4];
        #pragma unroll
        for (int i = 0; i < 4; ++i) {
            pk0[i] = f2bf(o0[4 * g + i] * rl);
            pk1[i] = f2bf(o1[4 * g + i] * rl);
        }
        const int d0 = 8 * g + 4 * hi;
        *reinterpret_cast<int2*>(orow + d0) = *reinterpret_cast<const int2*>(pk0);
        *reinterpret_cast<int2*>(orow + 32 + d0) = *reinterpret_cast<const int2*>(pk1);
    }
}

// ---------------------------------------------------------------------------
// Launch
// ---------------------------------------------------------------------------
extern "C" void kernel_launch(void* const* d_in, const int* in_sizes, int n_in,
                              void* d_out, int out_size, void* d_ws, size_t ws_size,
                              hipStream_t stream)
{
    (void)in_sizes; (void)n_in; (void)out_size; (void)ws_size;
    const float* x      = (const float*)d_in[0];
    const int*   mask   = (const int*)d_in[1];
    const float* ln1_g  = (const float*)d_in[2];
    const float* ln1_b  = (const float*)d_in[3];
    const float* qkv_w  = (const float*)d_in[4];
    const float* qkv_b  = (const float*)d_in[5];
    const float* proj_w = (const float*)d_in[6];
    const float* proj_b = (const float*)d_in[7];
    const float* ln2_g  = (const float*)d_in[8];
    const float* ln2_b  = (const float*)d_in[9];
    const float* fc1_w  = (const float*)d_in[10];
    const float* fc1_b  = (const float*)d_in[11];
    const float* fc2_w  = (const float*)d_in[12];
    const float* fc2_b  = (const float*)d_in[13];
    float* out = (float*)d_out;
    char* ws = (char*)d_ws;

    bf16*  Wt_qkv  = (bf16*)(ws + 0);          // [2304][768]
    bf16*  Wt_proj = (bf16*)(ws + 3538944);    // [768][768]
    bf16*  Wt_fc1  = (bf16*)(ws + 4718592);    // [3072][768]
    bf16*  Wt_fc2  = (bf16*)(ws + 9437184);    // [768][3072]
    bf16*  hbuf    = (bf16*)(ws + 14155776);   // [8192][768]
    bf16*  attnout = (bf16*)(ws + 64487424);   // [8192][768]
    bf16*  x1      = (bf16*)(ws + 77070336);   // [8192][768] bf16 now
    bf16*  h2      = (bf16*)(ws + 102236160);  // [8192][768]
    bf16*  a1      = (bf16*)(ws + 114819072);  // [8192][3072] (FC1 out)
    bf16*  Qb      = (bf16*)(ws + 114819072);  // overlay: [4][12][2048][64]
    bf16*  Kb      = (bf16*)(ws + 127401984);
    bf16*  Vt      = (bf16*)(ws + 139984896);

    transpose_all<<<6912, dim3(32, 8), 0, stream>>>(
        qkv_w, proj_w, fc1_w, fc2_w, Wt_qkv, Wt_proj, Wt_fc1, Wt_fc2);

    ln_kernel<<<2048, 256, 0, stream>>>(x, ln1_g, ln1_b, hbuf);
    gemm256<3><<<dim3(32, 18), 512, 0, stream>>>(hbuf, Wt_qkv, qkv_b, nullptr,
                                                 mask, Qb, Kb, Vt, 8192, 2304, 768);
    attn_kernel<<<768, 256, 0, stream>>>(Qb, Kb, Vt, attnout);
    gemm64<0><<<dim3(128, 6), 256, 0, stream>>>(attnout, Wt_proj, proj_b, x, x1,
                                                8192, 768, 768);
    ln_bf16_kernel<<<2048, 256, 0, stream>>>(x1, ln2_g, ln2_b, h2);
    gemm256<2><<<dim3(32, 24), 512, 0, stream>>>(h2, Wt_fc1, fc1_b, a1,
                                                 nullptr, nullptr, nullptr, nullptr, 8192, 3072, 768);
    gemm64<1><<<dim3(128, 6), 256, 0, stream>>>(a1, Wt_fc2, fc2_b, x1, out,
                                                8192, 768, 3072);
}

// Round 15
// 236.272 us; speedup vs baseline: 1.0714x; 1.0074x over previous
//
#include <hip/hip_runtime.h>
#include <hip/hip_bf16.h>
#include <math.h>

using bf16 = __hip_bfloat16;
typedef short s16x8 __attribute__((ext_vector_type(8)));
typedef float f32x4 __attribute__((ext_vector_type(4)));
typedef float f32x16 __attribute__((ext_vector_type(16)));

#define LOG2E 1.4426950408889634f
// Q pre-scale: D^-0.5 * log2(e) so QK^T scores land directly in log2 domain.
#define QSCALE 0.18033688f

__device__ inline unsigned short f2bf(float f) {
    bf16 h = __float2bfloat16(f);
    return __builtin_bit_cast(unsigned short, h);
}

__device__ inline float bf2f(unsigned short u) {
    unsigned v = (unsigned)u << 16;
    return __builtin_bit_cast(float, v);
}

// async global->LDS, 16B per lane. Dest must be wave-linear (base + lane*16).
__device__ inline void gload_lds16(const void* g, void* l) {
    __builtin_amdgcn_global_load_lds(
        (const __attribute__((address_space(1))) void*)g,
        (__attribute__((address_space(3))) void*)l, 16, 0, 0);
}

__device__ inline unsigned cvtpk(float lo, float hi) {
    unsigned r;
    asm("v_cvt_pk_bf16_f32 %0, %1, %2" : "=v"(r) : "v"(lo), "v"(hi));
    return r;
}

// Build PV B-operand fragment from 8 in-lane P values (verified mapping).
__device__ inline s16x8 build_pfrag(float p0, float p1, float p2, float p3,
                                    float p4, float p5, float p6, float p7) {
    unsigned w01 = cvtpk(p0, p1);
    unsigned w23 = cvtpk(p2, p3);
    unsigned w45 = cvtpk(p4, p5);
    unsigned w67 = cvtpk(p6, p7);
    asm volatile("v_permlane32_swap_b32 %0, %1" : "+v"(w01), "+v"(w45));
    asm volatile("v_permlane32_swap_b32 %0, %1" : "+v"(w23), "+v"(w67));
    int4 t = {(int)w01, (int)w23, (int)w45, (int)w67};
    return __builtin_bit_cast(s16x8, t);
}

// ---------------------------------------------------------------------------
// Merged prep: 4 weight transposes (blocks 0..6911) + LN1 (blocks 6912..8959)
// in ONE launch — the two phases are independent and overlap on the device.
// ---------------------------------------------------------------------------
__global__ __launch_bounds__(256) void prep_kernel(
    const float* __restrict__ qkv_w, const float* __restrict__ proj_w,
    const float* __restrict__ fc1_w, const float* __restrict__ fc2_w,
    bf16* __restrict__ Wqkv, bf16* __restrict__ Wproj,
    bf16* __restrict__ Wfc1, bf16* __restrict__ Wfc2,
    const float* __restrict__ x, const float* __restrict__ g,
    const float* __restrict__ bb, bf16* __restrict__ outln)
{
    int t = blockIdx.x;
    if (t >= 6912) {
        // ---- LayerNorm: one wave per row, 4 rows per block ----
        const int wave = threadIdx.x >> 6, lane = threadIdx.x & 63;
        const int row = (t - 6912) * 4 + wave;
        const float* xr = x + (size_t)row * 768;
        float4 v[3];
        float s = 0.f, s2 = 0.f;
        #pragma unroll
        for (int i = 0; i < 3; ++i) {
            v[i] = *reinterpret_cast<const float4*>(xr + (lane + 64 * i) * 4);
            s += (v[i].x + v[i].y) + (v[i].z + v[i].w);
            s2 += (v[i].x * v[i].x + v[i].y * v[i].y) + (v[i].z * v[i].z + v[i].w * v[i].w);
        }
        #pragma unroll
        for (int off = 1; off < 64; off <<= 1) {
            s += __shfl_xor(s, off);
            s2 += __shfl_xor(s2, off);
        }
        const float mu = s * (1.f / 768.f);
        const float var = s2 * (1.f / 768.f) - mu * mu;
        const float r = rsqrtf(var + 1e-6f);
        bf16* orow = outln + (size_t)row * 768;
        #pragma unroll
        for (int i = 0; i < 3; ++i) {
            const int col = (lane + 64 * i) * 4;
            const float4 gg = *reinterpret_cast<const float4*>(g + col);
            const float4 bv = *reinterpret_cast<const float4*>(bb + col);
            unsigned short pk[4];
            pk[0] = f2bf((v[i].x - mu) * r * gg.x + bv.x);
            pk[1] = f2bf((v[i].y - mu) * r * gg.y + bv.y);
            pk[2] = f2bf((v[i].z - mu) * r * gg.z + bv.z);
            pk[3] = f2bf((v[i].w - mu) * r * gg.w + bv.w);
            *reinterpret_cast<int2*>(orow + col) = *reinterpret_cast<const int2*>(pk);
        }
        return;
    }
    // ---- weight transpose: 32x32 tile ----
    const float* in;
    bf16* out;
    int K, N, xt;
    if (t < 1728)      { in = qkv_w;  out = Wqkv;  K = 768;  N = 2304; xt = 72; }
    else if (t < 2304) { in = proj_w; out = Wproj; K = 768;  N = 768;  xt = 24; t -= 1728; }
    else if (t < 4608) { in = fc1_w;  out = Wfc1;  K = 768;  N = 3072; xt = 96; t -= 2304; }
    else               { in = fc2_w;  out = Wfc2;  K = 3072; N = 768;  xt = 24; t -= 4608; }
    const int bx = (t % xt) * 32;  // n
    const int by = (t / xt) * 32;  // k

    __shared__ float tile[32][33];
    const int tx = threadIdx.x & 31, ty = threadIdx.x >> 5;  // 32 x 8
    #pragma unroll
    for (int i = 0; i < 32; i += 8)
        tile[ty + i][tx] = in[(size_t)(by + ty + i) * N + bx + tx];
    __syncthreads();
    #pragma unroll
    for (int i = 0; i < 32; i += 8)
        out[(size_t)(bx + ty + i) * K + by + tx] = __float2bfloat16(tile[tx][ty + i]);
}

// ---------------------------------------------------------------------------
// LayerNorm, bf16 input variant (for x1). 12 bf16/lane: one 16B + one 8B load.
// ---------------------------------------------------------------------------
__global__ __launch_bounds__(256) void ln_bf16_kernel(
    const bf16* __restrict__ x, const float* __restrict__ g,
    const float* __restrict__ bb, bf16* __restrict__ out)
{
    const int wave = threadIdx.x >> 6, lane = threadIdx.x & 63;
    const int row = blockIdx.x * 4 + wave;
    const bf16* xr = x + (size_t)row * 768;
    unsigned short e[12];
    *reinterpret_cast<int4*>(e) = *reinterpret_cast<const int4*>(xr + lane * 8);
    *reinterpret_cast<int2*>(e + 8) = *reinterpret_cast<const int2*>(xr + 512 + lane * 4);
    float f[12];
    float s = 0.f, s2 = 0.f;
    #pragma unroll
    for (int i = 0; i < 12; ++i) {
        f[i] = bf2f(e[i]);
        s += f[i];
        s2 += f[i] * f[i];
    }
    #pragma unroll
    for (int off = 1; off < 64; off <<= 1) {
        s += __shfl_xor(s, off);
        s2 += __shfl_xor(s2, off);
    }
    const float mu = s * (1.f / 768.f);
    const float var = s2 * (1.f / 768.f) - mu * mu;
    const float r = rsqrtf(var + 1e-6f);
    bf16* orow = out + (size_t)row * 768;
    unsigned short pk[12];
    #pragma unroll
    for (int i = 0; i < 8; ++i) {
        const int col = lane * 8 + i;
        pk[i] = f2bf((f[i] - mu) * r * g[col] + bb[col]);
    }
    #pragma unroll
    for (int i = 0; i < 4; ++i) {
        const int col = 512 + lane * 4 + i;
        pk[8 + i] = f2bf((f[8 + i] - mu) * r * g[col] + bb[col]);
    }
    *reinterpret_cast<int4*>(orow + lane * 8) = *reinterpret_cast<const int4*>(pk);
    *reinterpret_cast<int2*>(orow + 512 + lane * 4) = *reinterpret_cast<const int2*>(pk + 8);
}

// ---------------------------------------------------------------------------
// GEMM 256x128, 8 waves (4M x 2N), single-buffer 2-barrier loop.
// EPI: 2 = bias+gelu -> bf16 ; 3 = fused QKV scatter.
// ---------------------------------------------------------------------------
template <int EPI>
__global__ __launch_bounds__(512) void gemm256(
    const bf16* __restrict__ A, const bf16* __restrict__ Bt,
    const float* __restrict__ bias,
    void* __restrict__ outp, const int* __restrict__ mask,
    bf16* __restrict__ Qb, bf16* __restrict__ Kb, bf16* __restrict__ Vt,
    int M, int N, int K)
{
    __shared__ alignas(16) char smem[65536];
    char* As = smem;            // 256 rows x 128B
    char* Bs = smem + 32768;    // 128 rows x 128B
    const int tid = threadIdx.x;
    const int lane = tid & 63;
    const int wave = tid >> 6;            // 0..7
    const int wm = wave >> 1, wn = wave & 1;
    const int lr = lane & 15, lg = lane >> 4;
    const int bm = blockIdx.x, bn = blockIdx.y;

    f32x4 acc[4][4] = {};

    const size_t a_row0 = (size_t)bm * 256;
    const size_t b_row0 = (size_t)bn * 128;

    for (int kt = 0; kt < K; kt += 64) {
        #pragma unroll
        for (int i = 0; i < 4; ++i) {
            const int id = tid + i * 512;
            const int row = id >> 3, c = id & 7;
            const int cs = (c ^ (row & 7)) * 8;
            gload_lds16(A + (a_row0 + row) * K + kt + cs, As + id * 16);
        }
        #pragma unroll
        for (int i = 0; i < 2; ++i) {
            const int id = tid + i * 512;
            const int row = id >> 3, c = id & 7;
            const int cs = (c ^ (row & 7)) * 8;
            gload_lds16(Bt + (b_row0 + row) * K + kt + cs, Bs + id * 16);
        }
        __syncthreads();
        #pragma unroll
        for (int ks = 0; ks < 2; ++ks) {
            s16x8 af[4], bfr[4];
            #pragma unroll
            for (int mf = 0; mf < 4; ++mf) {
                const int row = wm * 64 + mf * 16 + lr;
                const int c = ks * 4 + lg;
                af[mf] = *reinterpret_cast<const s16x8*>(As + row * 128 + ((c ^ (row & 7)) * 16));
            }
            #pragma unroll
            for (int nf = 0; nf < 4; ++nf) {
                const int row = wn * 64 + nf * 16 + lr;
                const int c = ks * 4 + lg;
                bfr[nf] = *reinterpret_cast<const s16x8*>(Bs + row * 128 + ((c ^ (row & 7)) * 16));
            }
            #pragma unroll
            for (int mf = 0; mf < 4; ++mf)
                #pragma unroll
                for (int nf = 0; nf < 4; ++nf)
                    acc[mf][nf] = __builtin_amdgcn_mfma_f32_16x16x32_bf16(
                        af[mf], bfr[nf], acc[mf][nf], 0, 0, 0);
        }
        __syncthreads();
    }

    if (EPI == 3) {
        const int rq = bn / 6;                       // 0=q, 1=k, 2=v
        const int bb_ = bm >> 3;                     // batch (2048/256 = 8 tiles)
        if (rq == 2) {
            char* Ws = smem + wave * 8192;
            #pragma unroll
            for (int nf = 0; nf < 4; ++nf) {
                const int cl = nf * 16 + lr;
                const int gn = bn * 128 + wn * 64 + nf * 16 + lr;
                const float bs = bias[gn];
                #pragma unroll
                for (int mf = 0; mf < 4; ++mf) {
                    unsigned short pk[4];
                    #pragma unroll
                    for (int i = 0; i < 4; ++i) pk[i] = f2bf(acc[mf][nf][i] + bs);
                    const int slot = (2 * mf + (lg >> 1)) ^ (cl & 7);
                    *reinterpret_cast<long long*>(Ws + cl * 128 + slot * 16 + (lg & 1) * 8) =
                        *reinterpret_cast<const long long*>(pk);
                }
            }
            __syncthreads();
            const int nb = (bm * 256 + wm * 64) & 2047;
            const int cb = (bn - 12) * 128 + wn * 64;
            #pragma unroll
            for (int r = 0; r < 8; ++r) {
                const int cl = r * 8 + (lane >> 3);
                const int j = lane & 7;
                const int4 vv = *reinterpret_cast<const int4*>(
                    Ws + cl * 128 + ((j ^ (cl & 7)) * 16));
                const int c = cb + cl;
                const int hh = c >> 6, dd = c & 63;
                *reinterpret_cast<int4*>(
                    Vt + ((size_t)(bb_ * 12 + hh) * 64 + dd) * 2048 + nb + j * 8) = vv;
            }
        } else {
            const int cb = bn * 128 - rq * 768 + wn * 64;
            bf16* dst = (rq == 0) ? Qb : Kb;
            #pragma unroll
            for (int mf = 0; mf < 4; ++mf) {
                #pragma unroll
                for (int i = 0; i < 4; ++i) {
                    const int gm = bm * 256 + wm * 64 + mf * 16 + 4 * lg + i;
                    const int n = gm & 2047;
                    const float msc = (rq == 0) ? (mask[gm] ? QSCALE : 0.f) : 1.f;
                    #pragma unroll
                    for (int nf = 0; nf < 4; ++nf) {
                        const int c = cb + nf * 16 + lr;
                        const int h = c >> 6, d = c & 63;
                        const int gn = bn * 128 + wn * 64 + nf * 16 + lr;
                        const float v = (acc[mf][nf][i] + bias[gn]) * msc;
                        dst[((size_t)(bb_ * 12 + h) * 2048 + n) * 64 + d] =
                            __float2bfloat16(v);
                    }
                }
            }
        }
        return;
    }

    #pragma unroll
    for (int mf = 0; mf < 4; ++mf) {
        #pragma unroll
        for (int i = 0; i < 4; ++i) {
            const int gm = bm * 256 + wm * 64 + mf * 16 + 4 * lg + i;
            #pragma unroll
            for (int nf = 0; nf < 4; ++nf) {
                const int gn = bn * 128 + wn * 64 + nf * 16 + lr;
                float v = acc[mf][nf][i] + bias[gn];
                if (EPI == 2) {
                    // gelu(x) = x - x/(1+e^{2y}), y = 0.79788456(x+0.044715x^3)
                    const float x3 = v * v * v;
                    const float z = fmaf(x3, 0.044715f, v) * 2.3022080f;
                    const float e = __builtin_amdgcn_exp2f(z);
                    v = v - v * __builtin_amdgcn_rcpf(1.f + e);
                }
                reinterpret_cast<bf16*>(outp)[(size_t)gm * N + gn] = __float2bfloat16(v);
            }
        }
    }
}

// ---------------------------------------------------------------------------
// GEMM 64x128 (grid-balanced, proj / FC2).
// EPI64: 0 = proj: resid fp32, out bf16 ; 1 = fc2: resid bf16, out fp32.
// ---------------------------------------------------------------------------
template <int EPI64>
__global__ __launch_bounds__(256) void gemm64(
    const bf16* __restrict__ A, const bf16* __restrict__ Bt,
    const float* __restrict__ bias, const void* __restrict__ resid,
    void* __restrict__ outp, int M, int N, int K)
{
    __shared__ alignas(16) char smem[24576];
    char* As = smem;             // 64 rows x 128B
    char* Bs = smem + 8192;      // 128 rows x 128B
    const int tid = threadIdx.x;
    const int lane = tid & 63;
    const int wn = tid >> 6;     // wave 0..3 -> N strip
    const int lr = lane & 15, lg = lane >> 4;
    const int bm = blockIdx.x, bn = blockIdx.y;

    f32x4 acc[4][2] = {};

    const size_t a_row0 = (size_t)bm * 64;
    const size_t b_row0 = (size_t)bn * 128;

    for (int kt = 0; kt < K; kt += 64) {
        #pragma unroll
        for (int i = 0; i < 2; ++i) {
            const int id = tid + i * 256;
            const int row = id >> 3, c = id & 7;
            const int cs = (c ^ (row & 7)) * 8;
            gload_lds16(A + (a_row0 + row) * K + kt + cs, As + id * 16);
        }
        #pragma unroll
        for (int i = 0; i < 4; ++i) {
            const int id = tid + i * 256;
            const int row = id >> 3, c = id & 7;
            const int cs = (c ^ (row & 7)) * 8;
            gload_lds16(Bt + (b_row0 + row) * K + kt + cs, Bs + id * 16);
        }
        __syncthreads();
        #pragma unroll
        for (int ks = 0; ks < 2; ++ks) {
            s16x8 af[4], bfr[2];
            #pragma unroll
            for (int mf = 0; mf < 4; ++mf) {
                const int row = mf * 16 + lr;
                const int c = ks * 4 + lg;
                af[mf] = *reinterpret_cast<const s16x8*>(As + row * 128 + ((c ^ (row & 7)) * 16));
            }
            #pragma unroll
            for (int nf = 0; nf < 2; ++nf) {
                const int row = wn * 32 + nf * 16 + lr;
                const int c = ks * 4 + lg;
                bfr[nf] = *reinterpret_cast<const s16x8*>(Bs + row * 128 + ((c ^ (row & 7)) * 16));
            }
            #pragma unroll
            for (int mf = 0; mf < 4; ++mf)
                #pragma unroll
                for (int nf = 0; nf < 2; ++nf)
                    acc[mf][nf] = __builtin_amdgcn_mfma_f32_16x16x32_bf16(
                        af[mf], bfr[nf], acc[mf][nf], 0, 0, 0);
        }
        __syncthreads();
    }

    #pragma unroll
    for (int mf = 0; mf < 4; ++mf) {
        #pragma unroll
        for (int i = 0; i < 4; ++i) {
            const int gm = bm * 64 + mf * 16 + 4 * lg + i;
            #pragma unroll
            for (int nf = 0; nf < 2; ++nf) {
                const int gn = bn * 128 + wn * 32 + nf * 16 + lr;
                const size_t idx = (size_t)gm * N + gn;
                float rv;
                if (EPI64 == 0) rv = reinterpret_cast<const float*>(resid)[idx];
                else            rv = __bfloat162float(reinterpret_cast<const bf16*>(resid)[idx]);
                const float v = acc[mf][nf][i] + bias[gn] + rv;
                if (EPI64 == 0)
                    reinterpret_cast<bf16*>(outp)[idx] = __float2bfloat16(v);
                else
                    reinterpret_cast<float*>(outp)[idx] = v;
            }
        }
    }
}

// ---------------------------------------------------------------------------
// Flash attention: static-max softmax (p = exp2(st)), ones-MFMA row sum,
// dbuf staging, XCD remap, conflict-free LDS swizzle.
// ---------------------------------------------------------------------------
__global__ __launch_bounds__(256, 3) void attn_kernel(
    const bf16* __restrict__ Qb, const bf16* __restrict__ Kb,
    const bf16* __restrict__ Vt, bf16* __restrict__ out)
{
    __shared__ alignas(16) char Ks[2][64 * 128];
    __shared__ alignas(16) char Vs[2][64 * 128];

    const int lin = blockIdx.x;            // 768 blocks
    const int xcd = lin & 7, slot = lin >> 3;
    const int pair = xcd * 6 + (slot >> 4);   // 0..47
    const int qb = slot & 15;
    const int b = pair / 12, h = pair % 12;

    const int tid = threadIdx.x, lane = tid & 63, wave = tid >> 6;
    const int lq = lane & 31;
    const int hi = lane >> 5;
    const size_t bh = (size_t)(b * 12 + h);
    const bf16* Kh = Kb + bh * 2048 * 64;
    const bf16* Vh = Vt + bh * 64 * 2048;
    const int q0w = qb * 128 + wave * 32;

    s16x8 qf[4];
    {
        const bf16* qp = Qb + (bh * 2048 + q0w + lq) * 64 + 8 * hi;
        #pragma unroll
        for (int ks = 0; ks < 4; ++ks)
            qf[ks] = *reinterpret_cast<const s16x8*>(qp + 16 * ks);
    }
    const int4 onesw = {0x3F803F80, 0x3F803F80, 0x3F803F80, 0x3F803F80};
    const s16x8 onesf = __builtin_bit_cast(s16x8, onesw);

    int sKoff0, sKoff1, dst0, dst1;
    size_t sVoff0, sVoff1;
    {
        const int id0 = tid;
        const int R0 = id0 >> 4;
        const int u0 = (id0 & 15) ^ (R0 & 15);
        const int rt0 = 2 * R0 + (u0 >> 3), s80 = (u0 & 7) * 8;
        sKoff0 = rt0 * 64 + s80;
        sVoff0 = (size_t)rt0 * 2048 + s80;
        dst0 = id0 * 16;
        const int id1 = tid + 256;
        const int R1 = id1 >> 4;
        const int u1 = (id1 & 15) ^ (R1 & 15);
        const int rt1 = 2 * R1 + (u1 >> 3), s81 = (u1 & 7) * 8;
        sKoff1 = rt1 * 64 + s81;
        sVoff1 = (size_t)rt1 * 2048 + s81;
        dst1 = id1 * 16;
    }

    const int rh = lq >> 1;
    const int m7 = rh & 7;
    const int rbase = rh * 256 + (((((lq & 1) << 3) ^ (rh & 8))) << 4);

    f32x16 o0 = {}, o1 = {};   // O^T accumulators: d 0..31 / 32..63
    f32x16 os = {};            // row-sum accumulator (all rows equal)

    #define STAGE(buf, kb)                                                    \
        do {                                                                  \
            gload_lds16(Kh + (kb) * 4096 + sKoff0, Ks[buf] + dst0);           \
            gload_lds16(Vh + (kb) * 64 + sVoff0, Vs[buf] + dst0);             \
            gload_lds16(Kh + (kb) * 4096 + sKoff1, Ks[buf] + dst1);           \
            gload_lds16(Vh + (kb) * 64 + sVoff1, Vs[buf] + dst1);             \
        } while (0)

    STAGE(0, 0);
    __syncthreads();
    int cur = 0;

    for (int kb = 0; kb < 32; ++kb) {
        if (kb < 31) STAGE(cur ^ 1, kb + 1);
        const char* Kc = Ks[cur] + rbase;
        const char* Vc = Vs[cur] + rbase;

        // ---- S^T (log2 domain) for both 32-key subtiles: 8 MFMAs ----
        f32x16 st0 = {}, st1 = {};
        __builtin_amdgcn_s_setprio(1);
        #pragma unroll
        for (int ks = 0; ks < 4; ++ks) {
            const int so = (((2 * ks + hi) ^ m7) << 4);
            const s16x8 kf0 = *reinterpret_cast<const s16x8*>(Kc + so);
            st0 = __builtin_amdgcn_mfma_f32_32x32x16_bf16(kf0, qf[ks], st0, 0, 0, 0);
            const s16x8 kf1 = *reinterpret_cast<const s16x8*>(Kc + 4096 + so);
            st1 = __builtin_amdgcn_mfma_f32_32x32x16_bf16(kf1, qf[ks], st1, 0, 0, 0);
        }
        __builtin_amdgcn_s_setprio(0);

        // ---- static-max softmax: p = exp2(st) ----
        float p0[16], p1[16];
        #pragma unroll
        for (int r = 0; r < 16; ++r) {
            p0[r] = __builtin_amdgcn_exp2f(st0[r]);
            p1[r] = __builtin_amdgcn_exp2f(st1[r]);
        }

        // ---- P^T B-frags (4 x 16 keys) ----
        const s16x8 pf00 = build_pfrag(p0[0], p0[1], p0[2], p0[3], p0[4], p0[5], p0[6], p0[7]);
        const s16x8 pf01 = build_pfrag(p0[8], p0[9], p0[10], p0[11], p0[12], p0[13], p0[14], p0[15]);
        const s16x8 pf10 = build_pfrag(p1[0], p1[1], p1[2], p1[3], p1[4], p1[5], p1[6], p1[7]);
        const s16x8 pf11 = build_pfrag(p1[8], p1[9], p1[10], p1[11], p1[12], p1[13], p1[14], p1[15]);

        // ---- O^T += V^T * P^T ; l += 1 . P (matrix pipe) ----
        __builtin_amdgcn_s_setprio(1);
        #pragma unroll
        for (int kf4 = 0; kf4 < 4; ++kf4) {
            const s16x8 pf = (kf4 == 0) ? pf00 : (kf4 == 1) ? pf01
                           : (kf4 == 2) ? pf10 : pf11;
            const int so = (((2 * kf4 + hi) ^ m7) << 4);
            const s16x8 vf0 = *reinterpret_cast<const s16x8*>(Vc + so);
            o0 = __builtin_amdgcn_mfma_f32_32x32x16_bf16(vf0, pf, o0, 0, 0, 0);
            const s16x8 vf1 = *reinterpret_cast<const s16x8*>(Vc + 4096 + so);
            o1 = __builtin_amdgcn_mfma_f32_32x32x16_bf16(vf1, pf, o1, 0, 0, 0);
            os = __builtin_amdgcn_mfma_f32_32x32x16_bf16(onesf, pf, os, 0, 0, 0);
        }
        __builtin_amdgcn_s_setprio(0);

        __syncthreads();
        cur ^= 1;
    }
    #undef STAGE

    const float rl = 1.0f / os[0];   // l for q = lane&31 (all rows equal)
    bf16* orow = out + (size_t)(b * 2048 + q0w + lq) * 768 + h * 64;
    #pragma unroll
    for (int g = 0; g < 4; ++g) {
        unsigned short pk0[4], pk1[4];
        #pragma unroll
        for (int i = 0; i < 4; ++i) {
            pk0[i] = f2bf(o0[4 * g + i] * rl);
            pk1[i] = f2bf(o1[4 * g + i] * rl);
        }
        const int d0 = 8 * g + 4 * hi;
        *reinterpret_cast<int2*>(orow + d0) = *reinterpret_cast<const int2*>(pk0);
        *reinterpret_cast<int2*>(orow + 32 + d0) = *reinterpret_cast<const int2*>(pk1);
    }
}

// ---------------------------------------------------------------------------
// Launch
// ---------------------------------------------------------------------------
extern "C" void kernel_launch(void* const* d_in, const int* in_sizes, int n_in,
                              void* d_out, int out_size, void* d_ws, size_t ws_size,
                              hipStream_t stream)
{
    (void)in_sizes; (void)n_in; (void)out_size; (void)ws_size;
    const float* x      = (const float*)d_in[0];
    const int*   mask   = (const int*)d_in[1];
    const float* ln1_g  = (const float*)d_in[2];
    const float* ln1_b  = (const float*)d_in[3];
    const float* qkv_w  = (const float*)d_in[4];
    const float* qkv_b  = (const float*)d_in[5];
    const float* proj_w = (const float*)d_in[6];
    const float* proj_b = (const float*)d_in[7];
    const float* ln2_g  = (const float*)d_in[8];
    const float* ln2_b  = (const float*)d_in[9];
    const float* fc1_w  = (const float*)d_in[10];
    const float* fc1_b  = (const float*)d_in[11];
    const float* fc2_w  = (const float*)d_in[12];
    const float* fc2_b  = (const float*)d_in[13];
    float* out = (float*)d_out;
    char* ws = (char*)d_ws;

    bf16*  Wt_qkv  = (bf16*)(ws + 0);          // [2304][768]
    bf16*  Wt_proj = (bf16*)(ws + 3538944);    // [768][768]
    bf16*  Wt_fc1  = (bf16*)(ws + 4718592);    // [3072][768]
    bf16*  Wt_fc2  = (bf16*)(ws + 9437184);    // [768][3072]
    bf16*  hbuf    = (bf16*)(ws + 14155776);   // [8192][768]
    bf16*  attnout = (bf16*)(ws + 64487424);   // [8192][768]
    bf16*  x1      = (bf16*)(ws + 77070336);   // [8192][768] bf16
    bf16*  h2      = (bf16*)(ws + 102236160);  // [8192][768]
    bf16*  a1      = (bf16*)(ws + 114819072);  // [8192][3072] (FC1 out)
    bf16*  Qb      = (bf16*)(ws + 114819072);  // overlay: [4][12][2048][64]
    bf16*  Kb      = (bf16*)(ws + 127401984);
    bf16*  Vt      = (bf16*)(ws + 139984896);

    prep_kernel<<<8960, 256, 0, stream>>>(
        qkv_w, proj_w, fc1_w, fc2_w, Wt_qkv, Wt_proj, Wt_fc1, Wt_fc2,
        x, ln1_g, ln1_b, hbuf);

    gemm256<3><<<dim3(32, 18), 512, 0, stream>>>(hbuf, Wt_qkv, qkv_b, nullptr,
                                                 mask, Qb, Kb, Vt, 8192, 2304, 768);
    attn_kernel<<<768, 256, 0, stream>>>(Qb, Kb, Vt, attnout);
    gemm64<0><<<dim3(128, 6), 256, 0, stream>>>(attnout, Wt_proj, proj_b, x, x1,
                                                8192, 768, 768);
    ln_bf16_kernel<<<2048, 256, 0, stream>>>(x1, ln2_g, ln2_b, h2);
    gemm256<2><<<dim3(32, 24), 512, 0, stream>>>(h2, Wt_fc1, fc1_b, a1,
                                                 nullptr, nullptr, nullptr, nullptr, 8192, 3072, 768);
    gemm64<1><<<dim3(128, 6), 256, 0, stream>>>(a1, Wt_fc2, fc2_b, x1, out,
                                                8192, 768, 3072);
}